// Round 1
// baseline (11151.553 us; speedup 1.0000x reference)
//
#include <hip/hip_runtime.h>
#include <hip/hip_bf16.h>

// GCN: h1 = relu(gcn(x, W1, b1)); h2 = relu(gcn(h1, W2, b2)); out = h2@Wl + bl
// gcn(x,W,b) = D^-1/2 (A+I) D^-1/2 (xW) + b, deg = in-degree(dst)+1

#define FEAT 128

__global__ __launch_bounds__(256) void hist_kernel(const int* __restrict__ dst,
                                                   int* __restrict__ cnt, long long E) {
    for (long long e = (long long)blockIdx.x * blockDim.x + threadIdx.x; e < E;
         e += (long long)gridDim.x * blockDim.x) {
        atomicAdd(&cnt[dst[e]], 1);
    }
}

__global__ __launch_bounds__(256) void dinv_kernel(const int* __restrict__ cnt,
                                                   float* __restrict__ dinv, int N) {
    int i = blockIdx.x * blockDim.x + threadIdx.x;
    if (i < N) dinv[i] = rsqrtf((float)(cnt[i] + 1));
}

// Y[M,128] = X[M,128] @ W[128,128] (+ bias). W staged in LDS (64KB).
// Block: 256 threads = 8 rows x 32 col-quads per iteration.
__global__ __launch_bounds__(256) void gemm128_kernel(const float* __restrict__ X,
                                                      const float* __restrict__ W,
                                                      const float* __restrict__ bias,
                                                      float* __restrict__ Y, int M) {
    __shared__ float sW[128 * 128];
    for (int i = threadIdx.x; i < 128 * 32; i += 256) {
        ((float4*)sW)[i] = ((const float4*)W)[i];
    }
    __syncthreads();

    const int lr = threadIdx.x >> 5;        // local row 0..7
    const int c4 = (threadIdx.x & 31) * 4;  // col base

    for (long long rg = blockIdx.x; rg * 8 < M; rg += gridDim.x) {
        long long row = rg * 8 + lr;
        if (row >= M) continue;
        const float4* xrow = (const float4*)(X + row * FEAT);
        float a0 = 0.f, a1 = 0.f, a2 = 0.f, a3 = 0.f;
#pragma unroll
        for (int k4 = 0; k4 < 32; ++k4) {
            float4 xv = xrow[k4];
            float4 w0 = *(const float4*)&sW[(4 * k4 + 0) * 128 + c4];
            float4 w1 = *(const float4*)&sW[(4 * k4 + 1) * 128 + c4];
            float4 w2 = *(const float4*)&sW[(4 * k4 + 2) * 128 + c4];
            float4 w3 = *(const float4*)&sW[(4 * k4 + 3) * 128 + c4];
            a0 += xv.x * w0.x + xv.y * w1.x + xv.z * w2.x + xv.w * w3.x;
            a1 += xv.x * w0.y + xv.y * w1.y + xv.z * w2.y + xv.w * w3.y;
            a2 += xv.x * w0.z + xv.y * w1.z + xv.z * w2.z + xv.w * w3.z;
            a3 += xv.x * w0.w + xv.y * w1.w + xv.z * w2.w + xv.w * w3.w;
        }
        float4 r;
        if (bias) {
            r.x = a0 + bias[c4 + 0]; r.y = a1 + bias[c4 + 1];
            r.z = a2 + bias[c4 + 2]; r.w = a3 + bias[c4 + 3];
        } else {
            r.x = a0; r.y = a1; r.z = a2; r.w = a3;
        }
        *(float4*)&Y[row * FEAT + c4] = r;
    }
}

// Edge-parallel scatter: 32 work-lanes per edge, each handles 4 feats.
__global__ __launch_bounds__(256) void scatter_kernel(const int* __restrict__ src,
                                                      const int* __restrict__ dst,
                                                      const float* __restrict__ dinv,
                                                      const float* __restrict__ P,
                                                      float* __restrict__ AGG, long long E) {
    long long total = E * 32;
    for (long long idx = (long long)blockIdx.x * blockDim.x + threadIdx.x; idx < total;
         idx += (long long)gridDim.x * blockDim.x) {
        long long e = idx >> 5;
        int l = (int)(idx & 31);
        int s = src[e], d = dst[e];
        float norm = dinv[s] * dinv[d];
        float4 v = *(const float4*)&P[(long long)s * FEAT + l * 4];
        float* out = &AGG[(long long)d * FEAT + l * 4];
        atomicAdd(out + 0, v.x * norm);
        atomicAdd(out + 1, v.y * norm);
        atomicAdd(out + 2, v.z * norm);
        atomicAdd(out + 3, v.w * norm);
    }
}

// AGG = relu(AGG + P*dinv^2 + b), in place. relu optional (not used on last layer).
__global__ __launch_bounds__(256) void self_bias_relu_kernel(const float* __restrict__ P,
                                                             const float* __restrict__ dinv,
                                                             const float* __restrict__ b,
                                                             float* __restrict__ AGG,
                                                             int N, int doRelu) {
    long long total = (long long)N * 32;  // float4 units
    for (long long idx = (long long)blockIdx.x * blockDim.x + threadIdx.x; idx < total;
         idx += (long long)gridDim.x * blockDim.x) {
        long long n = idx >> 5;
        int l = (int)(idx & 31);
        float di = dinv[n];
        float s = di * di;
        float4 p = *(const float4*)&P[n * FEAT + l * 4];
        float4 a = *(float4*)&AGG[n * FEAT + l * 4];
        float4 bb = *(const float4*)&b[l * 4];
        float4 r;
        r.x = a.x + p.x * s + bb.x;
        r.y = a.y + p.y * s + bb.y;
        r.z = a.z + p.z * s + bb.z;
        r.w = a.w + p.w * s + bb.w;
        if (doRelu) {
            r.x = fmaxf(r.x, 0.f); r.y = fmaxf(r.y, 0.f);
            r.z = fmaxf(r.z, 0.f); r.w = fmaxf(r.w, 0.f);
        }
        *(float4*)&AGG[n * FEAT + l * 4] = r;
    }
}

extern "C" void kernel_launch(void* const* d_in, const int* in_sizes, int n_in,
                              void* d_out, int out_size, void* d_ws, size_t ws_size,
                              hipStream_t stream) {
    const float* x  = (const float*)d_in[0];
    const int*   ei = (const int*)d_in[1];
    const float* W1 = (const float*)d_in[2];
    const float* b1 = (const float*)d_in[3];
    const float* W2 = (const float*)d_in[4];
    const float* b2 = (const float*)d_in[5];
    const float* Wl = (const float*)d_in[6];
    const float* bl = (const float*)d_in[7];
    float* out = (float*)d_out;

    const int N = in_sizes[0] / FEAT;          // 100000
    const long long E = in_sizes[1] / 2;       // 3200000
    const int* src = ei;
    const int* dst = ei + E;

    // workspace layout
    char* ws = (char*)d_ws;
    float* P    = (float*)ws;                          // N*128 f32
    float* AGG  = P + (long long)N * FEAT;             // N*128 f32
    int*   cnt  = (int*)(AGG + (long long)N * FEAT);   // N int
    float* dinv = (float*)(cnt + N);                   // N f32

    const size_t featBytes = (size_t)N * FEAT * sizeof(float);

    // degrees + dinv (recomputed each call; ws is not re-poisoned but we re-init)
    hipMemsetAsync(cnt, 0, (size_t)N * sizeof(int), stream);
    hipMemsetAsync(AGG, 0, featBytes, stream);
    hist_kernel<<<4096, 256, 0, stream>>>(dst, cnt, E);
    dinv_kernel<<<(N + 255) / 256, 256, 0, stream>>>(cnt, dinv, N);

    // ---- layer 1 ----
    gemm128_kernel<<<2048, 256, 0, stream>>>(x, W1, nullptr, P, N);
    scatter_kernel<<<8192, 256, 0, stream>>>(src, dst, dinv, P, AGG, E);
    self_bias_relu_kernel<<<4096, 256, 0, stream>>>(P, dinv, b1, AGG, N, 1);
    // AGG now holds h1

    // ---- layer 2 ----
    gemm128_kernel<<<2048, 256, 0, stream>>>(AGG, W2, nullptr, P, N);
    hipMemsetAsync(AGG, 0, featBytes, stream);
    scatter_kernel<<<8192, 256, 0, stream>>>(src, dst, dinv, P, AGG, E);
    self_bias_relu_kernel<<<4096, 256, 0, stream>>>(P, dinv, b2, AGG, N, 1);
    // AGG now holds h2

    // ---- output head ----
    gemm128_kernel<<<2048, 256, 0, stream>>>(AGG, Wl, bl, out, N);
}

// Round 2
// 1093.109 us; speedup vs baseline: 10.2017x; 10.2017x over previous
//
#include <hip/hip_runtime.h>
#include <hip/hip_bf16.h>

// GCN: h1 = relu(gcn(x, W1, b1)); h2 = relu(gcn(h1, W2, b2)); out = h2@Wl + bl
// gcn(x,W,b) = D^-1/2 (A+I) D^-1/2 (xW) + b, deg = in-degree(dst)+1
// Aggregation is done GATHER-style over a per-call-built CSR (sorted by dst):
//   agg[n] = dinv[n] * ( dinv[n]*P[n] + sum_{e: dst=n} dinv[src_e]*P[src_e] ) + b

#define FEAT 128

// ---------- degree histogram ----------
__global__ __launch_bounds__(256) void hist_kernel(const int* __restrict__ dst,
                                                   int* __restrict__ cnt, long long E) {
    for (long long e = (long long)blockIdx.x * blockDim.x + threadIdx.x; e < E;
         e += (long long)gridDim.x * blockDim.x) {
        atomicAdd(&cnt[dst[e]], 1);
    }
}

__global__ __launch_bounds__(256) void dinv_kernel(const int* __restrict__ cnt,
                                                   float* __restrict__ dinv, int N) {
    int i = blockIdx.x * blockDim.x + threadIdx.x;
    if (i < N) dinv[i] = rsqrtf((float)(cnt[i] + 1));
}

// ---------- 3-kernel exclusive scan of cnt[N] -> row_ptr[N+1], next[N] ----------
__global__ __launch_bounds__(256) void scan_blocksums_kernel(const int* __restrict__ cnt,
                                                             int* __restrict__ bsum, int N) {
    __shared__ int tmp[256];
    int i = blockIdx.x * 256 + threadIdx.x;
    int v = (i < N) ? cnt[i] : 0;
    tmp[threadIdx.x] = v;
    __syncthreads();
    for (int off = 128; off > 0; off >>= 1) {
        if (threadIdx.x < off) tmp[threadIdx.x] += tmp[threadIdx.x + off];
        __syncthreads();
    }
    if (threadIdx.x == 0) bsum[blockIdx.x] = tmp[0];
}

// single block: exclusive scan of bsum[nb] in place; writes row_ptr[N] = total
__global__ __launch_bounds__(512) void scan_offsets_kernel(int* __restrict__ bsum, int nb,
                                                           int* __restrict__ row_ptr, int N) {
    __shared__ int tmp[512];
    int t = threadIdx.x;
    int v = (t < nb) ? bsum[t] : 0;
    tmp[t] = v;
    __syncthreads();
    for (int off = 1; off < 512; off <<= 1) {
        int a = (t >= off) ? tmp[t - off] : 0;
        __syncthreads();
        tmp[t] += a;
        __syncthreads();
    }
    if (t < nb) bsum[t] = tmp[t] - v;  // exclusive
    if (t == 0) row_ptr[N] = tmp[nb - 1];
}

__global__ __launch_bounds__(256) void scan_final_kernel(const int* __restrict__ cnt,
                                                         const int* __restrict__ bsum,
                                                         int* __restrict__ row_ptr,
                                                         int* __restrict__ next, int N) {
    __shared__ int tmp[256];
    int i = blockIdx.x * 256 + threadIdx.x;
    int v = (i < N) ? cnt[i] : 0;
    tmp[threadIdx.x] = v;
    __syncthreads();
    for (int off = 1; off < 256; off <<= 1) {
        int a = (threadIdx.x >= off) ? tmp[threadIdx.x - off] : 0;
        __syncthreads();
        tmp[threadIdx.x] += a;
        __syncthreads();
    }
    if (i < N) {
        int excl = tmp[threadIdx.x] - v + bsum[blockIdx.x];
        row_ptr[i] = excl;
        next[i] = excl;
    }
}

// ---------- CSR fill: col[slot] = src, slots grouped by dst ----------
__global__ __launch_bounds__(256) void fill_kernel(const int* __restrict__ src,
                                                   const int* __restrict__ dst,
                                                   int* __restrict__ next,
                                                   int* __restrict__ col, long long E) {
    for (long long e = (long long)blockIdx.x * blockDim.x + threadIdx.x; e < E;
         e += (long long)gridDim.x * blockDim.x) {
        int p = atomicAdd(&next[dst[e]], 1);
        col[p] = src[e];
    }
}

// ---------- Y[M,128] = X[M,128] @ W[128,128] (+ bias), W in LDS ----------
__global__ __launch_bounds__(256) void gemm128_kernel(const float* __restrict__ X,
                                                      const float* __restrict__ W,
                                                      const float* __restrict__ bias,
                                                      float* __restrict__ Y, int M) {
    __shared__ float sW[128 * 128];
    for (int i = threadIdx.x; i < 128 * 32; i += 256) {
        ((float4*)sW)[i] = ((const float4*)W)[i];
    }
    __syncthreads();

    const int lr = threadIdx.x >> 5;        // local row 0..7
    const int c4 = (threadIdx.x & 31) * 4;  // col base

    for (long long rg = blockIdx.x; rg * 8 < M; rg += gridDim.x) {
        long long row = rg * 8 + lr;
        if (row >= M) continue;
        const float4* xrow = (const float4*)(X + row * FEAT);
        float a0 = 0.f, a1 = 0.f, a2 = 0.f, a3 = 0.f;
#pragma unroll
        for (int k4 = 0; k4 < 32; ++k4) {
            float4 xv = xrow[k4];
            float4 w0 = *(const float4*)&sW[(4 * k4 + 0) * 128 + c4];
            float4 w1 = *(const float4*)&sW[(4 * k4 + 1) * 128 + c4];
            float4 w2 = *(const float4*)&sW[(4 * k4 + 2) * 128 + c4];
            float4 w3 = *(const float4*)&sW[(4 * k4 + 3) * 128 + c4];
            a0 += xv.x * w0.x + xv.y * w1.x + xv.z * w2.x + xv.w * w3.x;
            a1 += xv.x * w0.y + xv.y * w1.y + xv.z * w2.y + xv.w * w3.y;
            a2 += xv.x * w0.z + xv.y * w1.z + xv.z * w2.z + xv.w * w3.z;
            a3 += xv.x * w0.w + xv.y * w1.w + xv.z * w2.w + xv.w * w3.w;
        }
        float4 r;
        if (bias) {
            r.x = a0 + bias[c4 + 0]; r.y = a1 + bias[c4 + 1];
            r.z = a2 + bias[c4 + 2]; r.w = a3 + bias[c4 + 3];
        } else {
            r.x = a0; r.y = a1; r.z = a2; r.w = a3;
        }
        *(float4*)&Y[row * FEAT + c4] = r;
    }
}

// ---------- gather-aggregate + self-loop + bias + relu, one 32-lane group/node ----------
__global__ __launch_bounds__(256) void gather_kernel(const int* __restrict__ row_ptr,
                                                     const int* __restrict__ col,
                                                     const float* __restrict__ dinv,
                                                     const float* __restrict__ P,
                                                     const float* __restrict__ bias,
                                                     float* __restrict__ OUT,
                                                     int N, int doRelu) {
    const int lane = threadIdx.x & 31;
    const int grp = threadIdx.x >> 5;                   // 0..7
    const int n = blockIdx.x * 8 + grp;
    if (n >= N) return;

    const float di = dinv[n];
    const int f4 = lane * 4;

    // self-loop init: acc = di * P[n]; final acc *= di gives di^2 * P[n]
    float4 acc = *(const float4*)&P[(long long)n * FEAT + f4];
    acc.x *= di; acc.y *= di; acc.z *= di; acc.w *= di;

    const int start = row_ptr[n];
    const int end = row_ptr[n + 1];

    for (int e0 = start; e0 < end; e0 += 32) {
        int mye = e0 + lane;
        int s = (mye < end) ? col[mye] : 0;
        float w = (mye < end) ? dinv[s] : 0.0f;
        int jmax = end - e0; if (jmax > 32) jmax = 32;
        int j = 0;
        for (; j + 1 < jmax; j += 2) {
            int s0 = __shfl(s, j, 32);      float w0 = __shfl(w, j, 32);
            int s1 = __shfl(s, j + 1, 32);  float w1 = __shfl(w, j + 1, 32);
            float4 v0 = *(const float4*)&P[(long long)s0 * FEAT + f4];
            float4 v1 = *(const float4*)&P[(long long)s1 * FEAT + f4];
            acc.x += v0.x * w0; acc.y += v0.y * w0; acc.z += v0.z * w0; acc.w += v0.w * w0;
            acc.x += v1.x * w1; acc.y += v1.y * w1; acc.z += v1.z * w1; acc.w += v1.w * w1;
        }
        if (j < jmax) {
            int s0 = __shfl(s, j, 32); float w0 = __shfl(w, j, 32);
            float4 v0 = *(const float4*)&P[(long long)s0 * FEAT + f4];
            acc.x += v0.x * w0; acc.y += v0.y * w0; acc.z += v0.z * w0; acc.w += v0.w * w0;
        }
    }

    float4 bb = *(const float4*)&bias[f4];
    float4 r;
    r.x = acc.x * di + bb.x;
    r.y = acc.y * di + bb.y;
    r.z = acc.z * di + bb.z;
    r.w = acc.w * di + bb.w;
    if (doRelu) {
        r.x = fmaxf(r.x, 0.f); r.y = fmaxf(r.y, 0.f);
        r.z = fmaxf(r.z, 0.f); r.w = fmaxf(r.w, 0.f);
    }
    *(float4*)&OUT[(long long)n * FEAT + f4] = r;
}

extern "C" void kernel_launch(void* const* d_in, const int* in_sizes, int n_in,
                              void* d_out, int out_size, void* d_ws, size_t ws_size,
                              hipStream_t stream) {
    const float* x  = (const float*)d_in[0];
    const int*   ei = (const int*)d_in[1];
    const float* W1 = (const float*)d_in[2];
    const float* b1 = (const float*)d_in[3];
    const float* W2 = (const float*)d_in[4];
    const float* b2 = (const float*)d_in[5];
    const float* Wl = (const float*)d_in[6];
    const float* bl = (const float*)d_in[7];
    float* out = (float*)d_out;

    const int N = in_sizes[0] / FEAT;      // 100000
    const long long E = in_sizes[1] / 2;   // 3200000
    const int* src = ei;
    const int* dst = ei + E;

    const int nb = (N + 255) / 256;        // scan blocks (391)

    // workspace layout (~117 MB)
    float* A       = (float*)d_ws;                   // N*128 f32
    float* B       = A + (long long)N * FEAT;        // N*128 f32
    float* dinv    = B + (long long)N * FEAT;        // N f32
    int*   cnt     = (int*)(dinv + N);               // N
    int*   row_ptr = cnt + N;                        // N+1
    int*   next    = row_ptr + N + 1;                // N
    int*   bsum    = next + N;                       // 512
    int*   col     = bsum + 512;                     // E

    // ---- CSR build + dinv ----
    hipMemsetAsync(cnt, 0, (size_t)N * sizeof(int), stream);
    hist_kernel<<<4096, 256, 0, stream>>>(dst, cnt, E);
    dinv_kernel<<<nb, 256, 0, stream>>>(cnt, dinv, N);
    scan_blocksums_kernel<<<nb, 256, 0, stream>>>(cnt, bsum, N);
    scan_offsets_kernel<<<1, 512, 0, stream>>>(bsum, nb, row_ptr, N);
    scan_final_kernel<<<nb, 256, 0, stream>>>(cnt, bsum, row_ptr, next, N);
    fill_kernel<<<4096, 256, 0, stream>>>(src, dst, next, col, E);

    const int gatherBlocks = (N + 7) / 8;

    // ---- layer 1 ----
    gemm128_kernel<<<2048, 256, 0, stream>>>(x, W1, nullptr, A, N);
    gather_kernel<<<gatherBlocks, 256, 0, stream>>>(row_ptr, col, dinv, A, b1, B, N, 1);

    // ---- layer 2 ----
    gemm128_kernel<<<2048, 256, 0, stream>>>(B, W2, nullptr, A, N);
    gather_kernel<<<gatherBlocks, 256, 0, stream>>>(row_ptr, col, dinv, A, b2, B, N, 1);

    // ---- output head ----
    gemm128_kernel<<<2048, 256, 0, stream>>>(B, Wl, bl, out, N);
}

// Round 3
// 968.348 us; speedup vs baseline: 11.5161x; 1.1288x over previous
//
#include <hip/hip_runtime.h>
#include <hip/hip_bf16.h>

// GCN: h1 = relu(gcn(x, W1, b1)); h2 = relu(gcn(h1, W2, b2)); out = h2@Wl + bl
// gcn(x,W,b) = D^-1/2 (A+I) D^-1/2 (xW) + b, deg = in-degree(dst)+1
// Aggregation: gather over per-call-built CSR. CSR fill uses a bucket-radix
// (dst>>9) so global writes are packed lines and atomics stay L2-resident.

#define FEAT 128
#define EPB 4096   // edges per radix chunk
#define NPB_SHIFT 9  // 512 nodes per bucket

// ---------- degree histogram ----------
__global__ __launch_bounds__(256) void hist_kernel(const int* __restrict__ dst,
                                                   int* __restrict__ cnt, long long E) {
    for (long long e = (long long)blockIdx.x * blockDim.x + threadIdx.x; e < E;
         e += (long long)gridDim.x * blockDim.x) {
        atomicAdd(&cnt[dst[e]], 1);
    }
}

__global__ __launch_bounds__(256) void dinv_kernel(const int* __restrict__ cnt,
                                                   float* __restrict__ dinv, int N) {
    int i = blockIdx.x * blockDim.x + threadIdx.x;
    if (i < N) dinv[i] = rsqrtf((float)(cnt[i] + 1));
}

// ---------- node-count scan -> row_ptr, next ----------
__global__ __launch_bounds__(256) void scan_blocksums_kernel(const int* __restrict__ cnt,
                                                             int* __restrict__ bsum, int N) {
    __shared__ int tmp[256];
    int i = blockIdx.x * 256 + threadIdx.x;
    int v = (i < N) ? cnt[i] : 0;
    tmp[threadIdx.x] = v;
    __syncthreads();
    for (int off = 128; off > 0; off >>= 1) {
        if (threadIdx.x < off) tmp[threadIdx.x] += tmp[threadIdx.x + off];
        __syncthreads();
    }
    if (threadIdx.x == 0) bsum[blockIdx.x] = tmp[0];
}

__global__ __launch_bounds__(512) void scan_offsets_kernel(int* __restrict__ bsum, int nb,
                                                           int* __restrict__ row_ptr, int N) {
    __shared__ int tmp[512];
    int t = threadIdx.x;
    int v = (t < nb) ? bsum[t] : 0;
    tmp[t] = v;
    __syncthreads();
    for (int off = 1; off < 512; off <<= 1) {
        int a = (t >= off) ? tmp[t - off] : 0;
        __syncthreads();
        tmp[t] += a;
        __syncthreads();
    }
    if (t < nb) bsum[t] = tmp[t] - v;  // exclusive
    if (t == 0) row_ptr[N] = tmp[nb - 1];
}

__global__ __launch_bounds__(256) void scan_final_kernel(const int* __restrict__ cnt,
                                                         const int* __restrict__ bsum,
                                                         int* __restrict__ row_ptr,
                                                         int* __restrict__ next, int N) {
    __shared__ int tmp[256];
    int i = blockIdx.x * 256 + threadIdx.x;
    int v = (i < N) ? cnt[i] : 0;
    tmp[threadIdx.x] = v;
    __syncthreads();
    for (int off = 1; off < 256; off <<= 1) {
        int a = (threadIdx.x >= off) ? tmp[threadIdx.x - off] : 0;
        __syncthreads();
        tmp[threadIdx.x] += a;
        __syncthreads();
    }
    if (i < N) {
        int excl = tmp[threadIdx.x] - v + bsum[blockIdx.x];
        row_ptr[i] = excl;
        next[i] = excl;
    }
}

// ---------- bucket radix: count per (bucket, chunk) ----------
__global__ __launch_bounds__(256) void radix_count_kernel(const int* __restrict__ dst,
                                                          int* __restrict__ cmat,
                                                          long long E, int nbuck, int nblk) {
    __shared__ int h[256];
    int blk = blockIdx.x;
    for (int i = threadIdx.x; i < nbuck; i += 256) h[i] = 0;
    __syncthreads();
    long long e0 = (long long)blk * EPB;
    long long eend = e0 + EPB; if (eend > E) eend = E;
    for (long long e = e0 + threadIdx.x; e < eend; e += 256)
        atomicAdd(&h[dst[e] >> NPB_SHIFT], 1);
    __syncthreads();
    for (int i = threadIdx.x; i < nbuck; i += 256)
        cmat[(long long)i * nblk + blk] = h[i];
}

// per-bucket totals (row sums of cmat)
__global__ __launch_bounds__(256) void radix_btot_kernel(const int* __restrict__ cmat,
                                                         int* __restrict__ btot, int nblk) {
    __shared__ int tmp[256];
    long long row = (long long)blockIdx.x * nblk;
    int s = 0;
    for (int i = threadIdx.x; i < nblk; i += 256) s += cmat[row + i];
    tmp[threadIdx.x] = s;
    __syncthreads();
    for (int off = 128; off > 0; off >>= 1) {
        if (threadIdx.x < off) tmp[threadIdx.x] += tmp[threadIdx.x + off];
        __syncthreads();
    }
    if (threadIdx.x == 0) btot[blockIdx.x] = tmp[0];
}

// exclusive scan of btot[nbuck] (nbuck <= 256) -> bbase
__global__ __launch_bounds__(256) void radix_bscan_kernel(const int* __restrict__ btot,
                                                          int* __restrict__ bbase, int nbuck) {
    __shared__ int tmp[256];
    int t = threadIdx.x;
    int v = (t < nbuck) ? btot[t] : 0;
    tmp[t] = v;
    __syncthreads();
    for (int off = 1; off < 256; off <<= 1) {
        int a = (t >= off) ? tmp[t - off] : 0;
        __syncthreads();
        tmp[t] += a;
        __syncthreads();
    }
    if (t < nbuck) bbase[t] = tmp[t] - v;
}

// per-bucket exclusive scan across chunks, offset by bbase
__global__ __launch_bounds__(256) void radix_colscan_kernel(int* __restrict__ cmat,
                                                            const int* __restrict__ bbase,
                                                            int nblk) {
    __shared__ int tmp[256];
    __shared__ int carry;
    long long row = (long long)blockIdx.x * nblk;
    if (threadIdx.x == 0) carry = bbase[blockIdx.x];
    __syncthreads();
    for (int c0 = 0; c0 < nblk; c0 += 256) {
        int i = c0 + threadIdx.x;
        int v = (i < nblk) ? cmat[row + i] : 0;
        tmp[threadIdx.x] = v;
        __syncthreads();
        for (int off = 1; off < 256; off <<= 1) {
            int a = (threadIdx.x >= off) ? tmp[threadIdx.x - off] : 0;
            __syncthreads();
            tmp[threadIdx.x] += a;
            __syncthreads();
        }
        if (i < nblk) cmat[row + i] = tmp[threadIdx.x] - v + carry;
        __syncthreads();
        if (threadIdx.x == 0) carry += tmp[255];
        __syncthreads();
    }
}

// scatter edges into bucket-ordered ebuf
__global__ __launch_bounds__(256) void radix_scatter_kernel(const int* __restrict__ src,
                                                            const int* __restrict__ dst,
                                                            const int* __restrict__ cmat,
                                                            int2* __restrict__ ebuf,
                                                            long long E, int nbuck, int nblk) {
    __shared__ int off[256];
    int blk = blockIdx.x;
    for (int i = threadIdx.x; i < nbuck; i += 256)
        off[i] = cmat[(long long)i * nblk + blk];
    __syncthreads();
    long long e0 = (long long)blk * EPB;
    long long eend = e0 + EPB; if (eend > E) eend = E;
    for (long long e = e0 + threadIdx.x; e < eend; e += 256) {
        int d = dst[e];
        int p = atomicAdd(&off[d >> NPB_SHIFT], 1);
        ebuf[p] = make_int2(src[e], d);
    }
}

// fill col from bucket-ordered ebuf; XCD-swizzled chunk map keeps each
// bucket's col/next lines on one XCD's L2.
__global__ __launch_bounds__(256) void radix_fill_kernel(const int2* __restrict__ ebuf,
                                                         int* __restrict__ next,
                                                         int* __restrict__ col,
                                                         long long E, int nchunks) {
    int g = blockIdx.x;
    int G = gridDim.x;                       // padded to multiple of 8
    int per = G >> 3;                        // chunks per XCD
    int c = (g & 7) * per + (g >> 3);        // bijective when G%8==0
    if (c >= nchunks) return;
    long long e0 = (long long)c * EPB;
    long long eend = e0 + EPB; if (eend > E) eend = E;
    for (long long e = e0 + threadIdx.x; e < eend; e += 256) {
        int2 sd = ebuf[e];
        int p = atomicAdd(&next[sd.y], 1);
        col[p] = sd.x;
    }
}

// ---------- Y[M,128] = X[M,128] @ W[128,128] (+ bias), W in LDS ----------
__global__ __launch_bounds__(256) void gemm128_kernel(const float* __restrict__ X,
                                                      const float* __restrict__ W,
                                                      const float* __restrict__ bias,
                                                      float* __restrict__ Y, int M) {
    __shared__ float sW[128 * 128];
    for (int i = threadIdx.x; i < 128 * 32; i += 256) {
        ((float4*)sW)[i] = ((const float4*)W)[i];
    }
    __syncthreads();

    const int lr = threadIdx.x >> 5;
    const int c4 = (threadIdx.x & 31) * 4;

    for (long long rg = blockIdx.x; rg * 8 < M; rg += gridDim.x) {
        long long row = rg * 8 + lr;
        if (row >= M) continue;
        const float4* xrow = (const float4*)(X + row * FEAT);
        float a0 = 0.f, a1 = 0.f, a2 = 0.f, a3 = 0.f;
#pragma unroll
        for (int k4 = 0; k4 < 32; ++k4) {
            float4 xv = xrow[k4];
            float4 w0 = *(const float4*)&sW[(4 * k4 + 0) * 128 + c4];
            float4 w1 = *(const float4*)&sW[(4 * k4 + 1) * 128 + c4];
            float4 w2 = *(const float4*)&sW[(4 * k4 + 2) * 128 + c4];
            float4 w3 = *(const float4*)&sW[(4 * k4 + 3) * 128 + c4];
            a0 += xv.x * w0.x + xv.y * w1.x + xv.z * w2.x + xv.w * w3.x;
            a1 += xv.x * w0.y + xv.y * w1.y + xv.z * w2.y + xv.w * w3.y;
            a2 += xv.x * w0.z + xv.y * w1.z + xv.z * w2.z + xv.w * w3.z;
            a3 += xv.x * w0.w + xv.y * w1.w + xv.z * w2.w + xv.w * w3.w;
        }
        float4 r;
        if (bias) {
            r.x = a0 + bias[c4 + 0]; r.y = a1 + bias[c4 + 1];
            r.z = a2 + bias[c4 + 2]; r.w = a3 + bias[c4 + 3];
        } else {
            r.x = a0; r.y = a1; r.z = a2; r.w = a3;
        }
        *(float4*)&Y[row * FEAT + c4] = r;
    }
}

// ---------- gather-aggregate + self-loop + bias + relu ----------
__global__ __launch_bounds__(256) void gather_kernel(const int* __restrict__ row_ptr,
                                                     const int* __restrict__ col,
                                                     const float* __restrict__ dinv,
                                                     const float* __restrict__ P,
                                                     const float* __restrict__ bias,
                                                     float* __restrict__ OUT,
                                                     int N, int doRelu) {
    const int lane = threadIdx.x & 31;
    const int grp = threadIdx.x >> 5;
    const int n = blockIdx.x * 8 + grp;
    if (n >= N) return;

    const float di = dinv[n];
    const int f4 = lane * 4;

    float4 acc = *(const float4*)&P[(long long)n * FEAT + f4];
    acc.x *= di; acc.y *= di; acc.z *= di; acc.w *= di;

    const int start = row_ptr[n];
    const int end = row_ptr[n + 1];

    for (int e0 = start; e0 < end; e0 += 32) {
        int mye = e0 + lane;
        int s = (mye < end) ? col[mye] : 0;
        float w = (mye < end) ? dinv[s] : 0.0f;
        int jmax = end - e0; if (jmax > 32) jmax = 32;
        int j = 0;
        for (; j + 1 < jmax; j += 2) {
            int s0 = __shfl(s, j, 32);      float w0 = __shfl(w, j, 32);
            int s1 = __shfl(s, j + 1, 32);  float w1 = __shfl(w, j + 1, 32);
            float4 v0 = *(const float4*)&P[(long long)s0 * FEAT + f4];
            float4 v1 = *(const float4*)&P[(long long)s1 * FEAT + f4];
            acc.x += v0.x * w0; acc.y += v0.y * w0; acc.z += v0.z * w0; acc.w += v0.w * w0;
            acc.x += v1.x * w1; acc.y += v1.y * w1; acc.z += v1.z * w1; acc.w += v1.w * w1;
        }
        if (j < jmax) {
            int s0 = __shfl(s, j, 32); float w0 = __shfl(w, j, 32);
            float4 v0 = *(const float4*)&P[(long long)s0 * FEAT + f4];
            acc.x += v0.x * w0; acc.y += v0.y * w0; acc.z += v0.z * w0; acc.w += v0.w * w0;
        }
    }

    float4 bb = *(const float4*)&bias[f4];
    float4 r;
    r.x = acc.x * di + bb.x;
    r.y = acc.y * di + bb.y;
    r.z = acc.z * di + bb.z;
    r.w = acc.w * di + bb.w;
    if (doRelu) {
        r.x = fmaxf(r.x, 0.f); r.y = fmaxf(r.y, 0.f);
        r.z = fmaxf(r.z, 0.f); r.w = fmaxf(r.w, 0.f);
    }
    *(float4*)&OUT[(long long)n * FEAT + f4] = r;
}

extern "C" void kernel_launch(void* const* d_in, const int* in_sizes, int n_in,
                              void* d_out, int out_size, void* d_ws, size_t ws_size,
                              hipStream_t stream) {
    const float* x  = (const float*)d_in[0];
    const int*   ei = (const int*)d_in[1];
    const float* W1 = (const float*)d_in[2];
    const float* b1 = (const float*)d_in[3];
    const float* W2 = (const float*)d_in[4];
    const float* b2 = (const float*)d_in[5];
    const float* Wl = (const float*)d_in[6];
    const float* bl = (const float*)d_in[7];
    float* out = (float*)d_out;

    const int N = in_sizes[0] / FEAT;      // 100000
    const long long E = in_sizes[1] / 2;   // 3200000
    const int* src = ei;
    const int* dst = ei + E;

    const int nb = (N + 255) / 256;                    // node-scan blocks
    const int nbuck = (N + (1 << NPB_SHIFT) - 1) >> NPB_SHIFT;  // 196
    const int nchunks = (int)((E + EPB - 1) / EPB);    // 782
    const int nblk = ((nchunks + 7) / 8) * 8;          // padded to 8 (784)

    // workspace layout (~118 MB)
    float* A       = (float*)d_ws;                     // N*128 f32 (aliases ebuf)
    float* B       = A + (long long)N * FEAT;          // N*128 f32
    float* dinv    = B + (long long)N * FEAT;          // N
    int*   cnt     = (int*)(dinv + N);                 // N
    int*   row_ptr = cnt + N;                          // N+1
    int*   next    = row_ptr + N + 1;                  // N
    int*   bsum    = next + N;                         // 512
    int*   btot    = bsum + 512;                       // 256
    int*   bbase   = btot + 256;                       // 256
    int*   cmat    = bbase + 256;                      // nbuck*nblk
    int*   col     = cmat + (long long)nbuck * nblk;   // E
    int2*  ebuf    = (int2*)A;                         // E int2 (51.2MB region)

    // ---- degrees + row_ptr ----
    hipMemsetAsync(cnt, 0, (size_t)N * sizeof(int), stream);
    hist_kernel<<<4096, 256, 0, stream>>>(dst, cnt, E);
    dinv_kernel<<<nb, 256, 0, stream>>>(cnt, dinv, N);
    scan_blocksums_kernel<<<nb, 256, 0, stream>>>(cnt, bsum, N);
    scan_offsets_kernel<<<1, 512, 0, stream>>>(bsum, nb, row_ptr, N);
    scan_final_kernel<<<nb, 256, 0, stream>>>(cnt, bsum, row_ptr, next, N);

    // ---- bucket radix CSR fill ----
    radix_count_kernel<<<nblk, 256, 0, stream>>>(dst, cmat, E, nbuck, nblk);
    radix_btot_kernel<<<nbuck, 256, 0, stream>>>(cmat, btot, nblk);
    radix_bscan_kernel<<<1, 256, 0, stream>>>(btot, bbase, nbuck);
    radix_colscan_kernel<<<nbuck, 256, 0, stream>>>(cmat, bbase, nblk);
    radix_scatter_kernel<<<nblk, 256, 0, stream>>>(src, dst, cmat, ebuf, E, nbuck, nblk);
    radix_fill_kernel<<<nblk, 256, 0, stream>>>(ebuf, next, col, E, nchunks);

    const int gatherBlocks = (N + 7) / 8;

    // ---- layer 1 ---- (gemm writes A only after ebuf is consumed)
    gemm128_kernel<<<2048, 256, 0, stream>>>(x, W1, nullptr, A, N);
    gather_kernel<<<gatherBlocks, 256, 0, stream>>>(row_ptr, col, dinv, A, b1, B, N, 1);

    // ---- layer 2 ----
    gemm128_kernel<<<2048, 256, 0, stream>>>(B, W2, nullptr, A, N);
    gather_kernel<<<gatherBlocks, 256, 0, stream>>>(row_ptr, col, dinv, A, b2, B, N, 1);

    // ---- output head ----
    gemm128_kernel<<<2048, 256, 0, stream>>>(B, Wl, bl, out, N);
}

// Round 4
// 740.142 us; speedup vs baseline: 15.0668x; 1.3083x over previous
//
#include <hip/hip_runtime.h>
#include <hip/hip_bf16.h>

// GCN: h1 = relu(gcn(x, W1, b1)); h2 = relu(gcn(h1, W2, b2)); out = h2@Wl + bl
// gcn(x,W,b) = D^-1/2 (A+I) D^-1/2 (xW) + b, deg = in-degree(dst)+1
// Gather-style aggregation over per-call-built CSR (bucket-radix fill).
// Projected features P stored in bf16 (halves gather traffic); all
// accumulation and hidden states stay fp32.

#define FEAT 128
#define EPB 4096     // edges per radix chunk
#define NPB_SHIFT 9  // 512 nodes per bucket

typedef unsigned short u16;
typedef unsigned int u32;

static __device__ __forceinline__ float bf_lo(u32 u) { return __uint_as_float(u << 16); }
static __device__ __forceinline__ float bf_hi(u32 u) { return __uint_as_float(u & 0xffff0000u); }
static __device__ __forceinline__ u16 f2b(float f) {
    __hip_bfloat16 h = __float2bfloat16(f);
    return *reinterpret_cast<u16*>(&h);
}

// ---------- degree histogram ----------
__global__ __launch_bounds__(256) void hist_kernel(const int* __restrict__ dst,
                                                   int* __restrict__ cnt, long long E) {
    for (long long e = (long long)blockIdx.x * blockDim.x + threadIdx.x; e < E;
         e += (long long)gridDim.x * blockDim.x) {
        atomicAdd(&cnt[dst[e]], 1);
    }
}

__global__ __launch_bounds__(256) void dinv_kernel(const int* __restrict__ cnt,
                                                   float* __restrict__ dinv, int N) {
    int i = blockIdx.x * blockDim.x + threadIdx.x;
    if (i < N) dinv[i] = rsqrtf((float)(cnt[i] + 1));
}

// ---------- node-count scan -> row_ptr, next ----------
__global__ __launch_bounds__(256) void scan_blocksums_kernel(const int* __restrict__ cnt,
                                                             int* __restrict__ bsum, int N) {
    __shared__ int tmp[256];
    int i = blockIdx.x * 256 + threadIdx.x;
    int v = (i < N) ? cnt[i] : 0;
    tmp[threadIdx.x] = v;
    __syncthreads();
    for (int off = 128; off > 0; off >>= 1) {
        if (threadIdx.x < off) tmp[threadIdx.x] += tmp[threadIdx.x + off];
        __syncthreads();
    }
    if (threadIdx.x == 0) bsum[blockIdx.x] = tmp[0];
}

__global__ __launch_bounds__(512) void scan_offsets_kernel(int* __restrict__ bsum, int nb,
                                                           int* __restrict__ row_ptr, int N) {
    __shared__ int tmp[512];
    int t = threadIdx.x;
    int v = (t < nb) ? bsum[t] : 0;
    tmp[t] = v;
    __syncthreads();
    for (int off = 1; off < 512; off <<= 1) {
        int a = (t >= off) ? tmp[t - off] : 0;
        __syncthreads();
        tmp[t] += a;
        __syncthreads();
    }
    if (t < nb) bsum[t] = tmp[t] - v;  // exclusive
    if (t == 0) row_ptr[N] = tmp[nb - 1];
}

__global__ __launch_bounds__(256) void scan_final_kernel(const int* __restrict__ cnt,
                                                         const int* __restrict__ bsum,
                                                         int* __restrict__ row_ptr,
                                                         int* __restrict__ next, int N) {
    __shared__ int tmp[256];
    int i = blockIdx.x * 256 + threadIdx.x;
    int v = (i < N) ? cnt[i] : 0;
    tmp[threadIdx.x] = v;
    __syncthreads();
    for (int off = 1; off < 256; off <<= 1) {
        int a = (threadIdx.x >= off) ? tmp[threadIdx.x - off] : 0;
        __syncthreads();
        tmp[threadIdx.x] += a;
        __syncthreads();
    }
    if (i < N) {
        int excl = tmp[threadIdx.x] - v + bsum[blockIdx.x];
        row_ptr[i] = excl;
        next[i] = excl;
    }
}

// ---------- bucket radix: count per (bucket, chunk) ----------
__global__ __launch_bounds__(256) void radix_count_kernel(const int* __restrict__ dst,
                                                          int* __restrict__ cmat,
                                                          long long E, int nbuck, int nblk) {
    __shared__ int h[256];
    int blk = blockIdx.x;
    for (int i = threadIdx.x; i < nbuck; i += 256) h[i] = 0;
    __syncthreads();
    long long e0 = (long long)blk * EPB;
    long long eend = e0 + EPB; if (eend > E) eend = E;
    for (long long e = e0 + threadIdx.x; e < eend; e += 256)
        atomicAdd(&h[dst[e] >> NPB_SHIFT], 1);
    __syncthreads();
    for (int i = threadIdx.x; i < nbuck; i += 256)
        cmat[(long long)i * nblk + blk] = h[i];
}

__global__ __launch_bounds__(256) void radix_btot_kernel(const int* __restrict__ cmat,
                                                         int* __restrict__ btot, int nblk) {
    __shared__ int tmp[256];
    long long row = (long long)blockIdx.x * nblk;
    int s = 0;
    for (int i = threadIdx.x; i < nblk; i += 256) s += cmat[row + i];
    tmp[threadIdx.x] = s;
    __syncthreads();
    for (int off = 128; off > 0; off >>= 1) {
        if (threadIdx.x < off) tmp[threadIdx.x] += tmp[threadIdx.x + off];
        __syncthreads();
    }
    if (threadIdx.x == 0) btot[blockIdx.x] = tmp[0];
}

__global__ __launch_bounds__(256) void radix_bscan_kernel(const int* __restrict__ btot,
                                                          int* __restrict__ bbase, int nbuck) {
    __shared__ int tmp[256];
    int t = threadIdx.x;
    int v = (t < nbuck) ? btot[t] : 0;
    tmp[t] = v;
    __syncthreads();
    for (int off = 1; off < 256; off <<= 1) {
        int a = (t >= off) ? tmp[t - off] : 0;
        __syncthreads();
        tmp[t] += a;
        __syncthreads();
    }
    if (t < nbuck) bbase[t] = tmp[t] - v;
}

__global__ __launch_bounds__(256) void radix_colscan_kernel(int* __restrict__ cmat,
                                                            const int* __restrict__ bbase,
                                                            int nblk) {
    __shared__ int tmp[256];
    __shared__ int carry;
    long long row = (long long)blockIdx.x * nblk;
    if (threadIdx.x == 0) carry = bbase[blockIdx.x];
    __syncthreads();
    for (int c0 = 0; c0 < nblk; c0 += 256) {
        int i = c0 + threadIdx.x;
        int v = (i < nblk) ? cmat[row + i] : 0;
        tmp[threadIdx.x] = v;
        __syncthreads();
        for (int off = 1; off < 256; off <<= 1) {
            int a = (threadIdx.x >= off) ? tmp[threadIdx.x - off] : 0;
            __syncthreads();
            tmp[threadIdx.x] += a;
            __syncthreads();
        }
        if (i < nblk) cmat[row + i] = tmp[threadIdx.x] - v + carry;
        __syncthreads();
        if (threadIdx.x == 0) carry += tmp[255];
        __syncthreads();
    }
}

__global__ __launch_bounds__(256) void radix_scatter_kernel(const int* __restrict__ src,
                                                            const int* __restrict__ dst,
                                                            const int* __restrict__ cmat,
                                                            int2* __restrict__ ebuf,
                                                            long long E, int nbuck, int nblk) {
    __shared__ int off[256];
    int blk = blockIdx.x;
    for (int i = threadIdx.x; i < nbuck; i += 256)
        off[i] = cmat[(long long)i * nblk + blk];
    __syncthreads();
    long long e0 = (long long)blk * EPB;
    long long eend = e0 + EPB; if (eend > E) eend = E;
    for (long long e = e0 + threadIdx.x; e < eend; e += 256) {
        int d = dst[e];
        int p = atomicAdd(&off[d >> NPB_SHIFT], 1);
        ebuf[p] = make_int2(src[e], d);
    }
}

__global__ __launch_bounds__(256) void radix_fill_kernel(const int2* __restrict__ ebuf,
                                                         int* __restrict__ next,
                                                         int* __restrict__ col,
                                                         long long E, int nchunks) {
    int g = blockIdx.x;
    int G = gridDim.x;
    int per = G >> 3;
    int c = (g & 7) * per + (g >> 3);
    if (c >= nchunks) return;
    long long e0 = (long long)c * EPB;
    long long eend = e0 + EPB; if (eend > E) eend = E;
    for (long long e = e0 + threadIdx.x; e < eend; e += 256) {
        int2 sd = ebuf[e];
        int p = atomicAdd(&next[sd.y], 1);
        col[p] = sd.x;
    }
}

// ---------- Y = X @ W (+ bias); output fp32 (Y) or bf16 (Yb) ----------
__global__ __launch_bounds__(256) void gemm128_kernel(const float* __restrict__ X,
                                                      const float* __restrict__ W,
                                                      const float* __restrict__ bias,
                                                      float* __restrict__ Y,
                                                      u16* __restrict__ Yb, int M) {
    __shared__ float sW[128 * 128];
    for (int i = threadIdx.x; i < 128 * 32; i += 256) {
        ((float4*)sW)[i] = ((const float4*)W)[i];
    }
    __syncthreads();

    const int lr = threadIdx.x >> 5;
    const int c4 = (threadIdx.x & 31) * 4;

    for (long long rg = blockIdx.x; rg * 8 < M; rg += gridDim.x) {
        long long row = rg * 8 + lr;
        if (row >= M) continue;
        const float4* xrow = (const float4*)(X + row * FEAT);
        float a0 = 0.f, a1 = 0.f, a2 = 0.f, a3 = 0.f;
#pragma unroll
        for (int k4 = 0; k4 < 32; ++k4) {
            float4 xv = xrow[k4];
            float4 w0 = *(const float4*)&sW[(4 * k4 + 0) * 128 + c4];
            float4 w1 = *(const float4*)&sW[(4 * k4 + 1) * 128 + c4];
            float4 w2 = *(const float4*)&sW[(4 * k4 + 2) * 128 + c4];
            float4 w3 = *(const float4*)&sW[(4 * k4 + 3) * 128 + c4];
            a0 += xv.x * w0.x + xv.y * w1.x + xv.z * w2.x + xv.w * w3.x;
            a1 += xv.x * w0.y + xv.y * w1.y + xv.z * w2.y + xv.w * w3.y;
            a2 += xv.x * w0.z + xv.y * w1.z + xv.z * w2.z + xv.w * w3.z;
            a3 += xv.x * w0.w + xv.y * w1.w + xv.z * w2.w + xv.w * w3.w;
        }
        if (bias) {
            a0 += bias[c4 + 0]; a1 += bias[c4 + 1];
            a2 += bias[c4 + 2]; a3 += bias[c4 + 3];
        }
        if (Yb) {
            ushort4 o;
            o.x = f2b(a0); o.y = f2b(a1); o.z = f2b(a2); o.w = f2b(a3);
            *(ushort4*)&Yb[row * FEAT + c4] = o;
        } else {
            float4 r; r.x = a0; r.y = a1; r.z = a2; r.w = a3;
            *(float4*)&Y[row * FEAT + c4] = r;
        }
    }
}

// ---------- gather-aggregate (bf16 P) + self-loop + bias + relu ----------
// 16 lanes per node row; each lane covers 8 feats (16B bf16 load).
__global__ __launch_bounds__(256) void gather_kernel(const int* __restrict__ row_ptr,
                                                     const int* __restrict__ col,
                                                     const float* __restrict__ dinv,
                                                     const u16* __restrict__ Pb,
                                                     const float* __restrict__ bias,
                                                     float* __restrict__ OUT,
                                                     int N, int doRelu) {
    const int lane = threadIdx.x & 15;
    const int grp = threadIdx.x >> 4;  // 0..15
    const int n = blockIdx.x * 16 + grp;
    if (n >= N) return;

    const float di = dinv[n];
    const int f8 = lane * 8;

    // self-loop init: acc = di * P[n]; final *di gives di^2 * P[n]
    uint4 sv = *(const uint4*)&Pb[(size_t)n * FEAT + f8];
    float a0 = bf_lo(sv.x) * di, a1 = bf_hi(sv.x) * di;
    float a2 = bf_lo(sv.y) * di, a3 = bf_hi(sv.y) * di;
    float a4 = bf_lo(sv.z) * di, a5 = bf_hi(sv.z) * di;
    float a6 = bf_lo(sv.w) * di, a7 = bf_hi(sv.w) * di;

    const int start = row_ptr[n];
    const int end = row_ptr[n + 1];

    for (int e0 = start; e0 < end; e0 += 16) {
        int mye = e0 + lane;
        int s = (mye < end) ? col[mye] : 0;
        float w = (mye < end) ? dinv[s] : 0.0f;
        int jmax = end - e0; if (jmax > 16) jmax = 16;
        int j = 0;
        for (; j + 3 < jmax; j += 4) {
            int s0 = __shfl(s, j, 16),     s1 = __shfl(s, j + 1, 16);
            int s2 = __shfl(s, j + 2, 16), s3 = __shfl(s, j + 3, 16);
            float w0 = __shfl(w, j, 16),     w1 = __shfl(w, j + 1, 16);
            float w2 = __shfl(w, j + 2, 16), w3 = __shfl(w, j + 3, 16);
            uint4 v0 = *(const uint4*)&Pb[(size_t)s0 * FEAT + f8];
            uint4 v1 = *(const uint4*)&Pb[(size_t)s1 * FEAT + f8];
            uint4 v2 = *(const uint4*)&Pb[(size_t)s2 * FEAT + f8];
            uint4 v3 = *(const uint4*)&Pb[(size_t)s3 * FEAT + f8];
            a0 += bf_lo(v0.x) * w0; a1 += bf_hi(v0.x) * w0;
            a2 += bf_lo(v0.y) * w0; a3 += bf_hi(v0.y) * w0;
            a4 += bf_lo(v0.z) * w0; a5 += bf_hi(v0.z) * w0;
            a6 += bf_lo(v0.w) * w0; a7 += bf_hi(v0.w) * w0;
            a0 += bf_lo(v1.x) * w1; a1 += bf_hi(v1.x) * w1;
            a2 += bf_lo(v1.y) * w1; a3 += bf_hi(v1.y) * w1;
            a4 += bf_lo(v1.z) * w1; a5 += bf_hi(v1.z) * w1;
            a6 += bf_lo(v1.w) * w1; a7 += bf_hi(v1.w) * w1;
            a0 += bf_lo(v2.x) * w2; a1 += bf_hi(v2.x) * w2;
            a2 += bf_lo(v2.y) * w2; a3 += bf_hi(v2.y) * w2;
            a4 += bf_lo(v2.z) * w2; a5 += bf_hi(v2.z) * w2;
            a6 += bf_lo(v2.w) * w2; a7 += bf_hi(v2.w) * w2;
            a0 += bf_lo(v3.x) * w3; a1 += bf_hi(v3.x) * w3;
            a2 += bf_lo(v3.y) * w3; a3 += bf_hi(v3.y) * w3;
            a4 += bf_lo(v3.z) * w3; a5 += bf_hi(v3.z) * w3;
            a6 += bf_lo(v3.w) * w3; a7 += bf_hi(v3.w) * w3;
        }
        for (; j < jmax; ++j) {
            int s0 = __shfl(s, j, 16);
            float w0 = __shfl(w, j, 16);
            uint4 v0 = *(const uint4*)&Pb[(size_t)s0 * FEAT + f8];
            a0 += bf_lo(v0.x) * w0; a1 += bf_hi(v0.x) * w0;
            a2 += bf_lo(v0.y) * w0; a3 += bf_hi(v0.y) * w0;
            a4 += bf_lo(v0.z) * w0; a5 += bf_hi(v0.z) * w0;
            a6 += bf_lo(v0.w) * w0; a7 += bf_hi(v0.w) * w0;
        }
    }

    const float4 b0 = *(const float4*)&bias[f8];
    const float4 b1 = *(const float4*)&bias[f8 + 4];
    float4 r0, r1;
    r0.x = a0 * di + b0.x; r0.y = a1 * di + b0.y;
    r0.z = a2 * di + b0.z; r0.w = a3 * di + b0.w;
    r1.x = a4 * di + b1.x; r1.y = a5 * di + b1.y;
    r1.z = a6 * di + b1.z; r1.w = a7 * di + b1.w;
    if (doRelu) {
        r0.x = fmaxf(r0.x, 0.f); r0.y = fmaxf(r0.y, 0.f);
        r0.z = fmaxf(r0.z, 0.f); r0.w = fmaxf(r0.w, 0.f);
        r1.x = fmaxf(r1.x, 0.f); r1.y = fmaxf(r1.y, 0.f);
        r1.z = fmaxf(r1.z, 0.f); r1.w = fmaxf(r1.w, 0.f);
    }
    *(float4*)&OUT[(size_t)n * FEAT + f8] = r0;
    *(float4*)&OUT[(size_t)n * FEAT + f8 + 4] = r1;
}

extern "C" void kernel_launch(void* const* d_in, const int* in_sizes, int n_in,
                              void* d_out, int out_size, void* d_ws, size_t ws_size,
                              hipStream_t stream) {
    const float* x  = (const float*)d_in[0];
    const int*   ei = (const int*)d_in[1];
    const float* W1 = (const float*)d_in[2];
    const float* b1 = (const float*)d_in[3];
    const float* W2 = (const float*)d_in[4];
    const float* b2 = (const float*)d_in[5];
    const float* Wl = (const float*)d_in[6];
    const float* bl = (const float*)d_in[7];
    float* out = (float*)d_out;

    const int N = in_sizes[0] / FEAT;      // 100000
    const long long E = in_sizes[1] / 2;   // 3200000
    const int* src = ei;
    const int* dst = ei + E;

    const int nb = (N + 255) / 256;
    const int nbuck = (N + (1 << NPB_SHIFT) - 1) >> NPB_SHIFT;  // 196
    const int nchunks = (int)((E + EPB - 1) / EPB);             // 782
    const int nblk = ((nchunks + 7) / 8) * 8;                   // 784

    // workspace layout (~92 MB)
    float* H       = (float*)d_ws;                     // N*128 f32 (aliases ebuf)
    u16*   Pb      = (u16*)(H + (long long)N * FEAT);  // N*128 bf16
    float* dinv    = (float*)(Pb + (long long)N * FEAT);
    int*   cnt     = (int*)(dinv + N);                 // N
    int*   row_ptr = cnt + N;                          // N+1
    int*   next    = row_ptr + N + 1;                  // N
    int*   bsum    = next + N;                         // 512
    int*   btot    = bsum + 512;                       // 256
    int*   bbase   = btot + 256;                       // 256
    int*   cmat    = bbase + 256;                      // nbuck*nblk
    int*   col     = cmat + (long long)nbuck * nblk;   // E
    int2*  ebuf    = (int2*)H;                         // E int2 (25.6MB, in H)

    // ---- degrees + row_ptr ----
    hipMemsetAsync(cnt, 0, (size_t)N * sizeof(int), stream);
    hist_kernel<<<4096, 256, 0, stream>>>(dst, cnt, E);
    dinv_kernel<<<nb, 256, 0, stream>>>(cnt, dinv, N);
    scan_blocksums_kernel<<<nb, 256, 0, stream>>>(cnt, bsum, N);
    scan_offsets_kernel<<<1, 512, 0, stream>>>(bsum, nb, row_ptr, N);
    scan_final_kernel<<<nb, 256, 0, stream>>>(cnt, bsum, row_ptr, next, N);

    // ---- bucket radix CSR fill ----
    radix_count_kernel<<<nblk, 256, 0, stream>>>(dst, cmat, E, nbuck, nblk);
    radix_btot_kernel<<<nbuck, 256, 0, stream>>>(cmat, btot, nblk);
    radix_bscan_kernel<<<1, 256, 0, stream>>>(btot, bbase, nbuck);
    radix_colscan_kernel<<<nbuck, 256, 0, stream>>>(cmat, bbase, nblk);
    radix_scatter_kernel<<<nblk, 256, 0, stream>>>(src, dst, cmat, ebuf, E, nbuck, nblk);
    radix_fill_kernel<<<nblk, 256, 0, stream>>>(ebuf, next, col, E, nchunks);

    const int gatherBlocks = (N + 15) / 16;

    // ---- layer 1 ---- (gemm writes Pb; ebuf already consumed)
    gemm128_kernel<<<2048, 256, 0, stream>>>(x, W1, nullptr, nullptr, Pb, N);
    gather_kernel<<<gatherBlocks, 256, 0, stream>>>(row_ptr, col, dinv, Pb, b1, H, N, 1);

    // ---- layer 2 ----
    gemm128_kernel<<<2048, 256, 0, stream>>>(H, W2, nullptr, nullptr, Pb, N);
    gather_kernel<<<gatherBlocks, 256, 0, stream>>>(row_ptr, col, dinv, Pb, b2, H, N, 1);

    // ---- output head ----
    gemm128_kernel<<<2048, 256, 0, stream>>>(H, Wl, bl, out, nullptr, N);
}

// Round 5
// 605.334 us; speedup vs baseline: 18.4222x; 1.2227x over previous
//
#include <hip/hip_runtime.h>
#include <hip/hip_bf16.h>

// GCN: h1 = relu(gcn(x, W1, b1)); h2 = relu(gcn(h1, W2, b2)); out = h2@Wl + bl
// gcn(x,W,b) = D^-1/2 (A+I) D^-1/2 (xW) + b, deg = in-degree(dst)+1
// Gather aggregation over per-call-built CSR (bucket-radix fill).
// Degree histogram is computed from the bucket-sorted edge buffer via LDS
// atomics (no random global atomics). P stored bf16; accum fp32.

#define FEAT 128
#define EPB 4096     // edges per radix chunk
#define NPB_SHIFT 9  // 512 nodes per bucket
#define HSPLIT 4     // blocks per bucket in bucket_hist

typedef unsigned short u16;
typedef unsigned int u32;

static __device__ __forceinline__ float bf_lo(u32 u) { return __uint_as_float(u << 16); }
static __device__ __forceinline__ float bf_hi(u32 u) { return __uint_as_float(u & 0xffff0000u); }
static __device__ __forceinline__ u16 f2b(float f) {
    __hip_bfloat16 h = __float2bfloat16(f);
    return *reinterpret_cast<u16*>(&h);
}

__global__ __launch_bounds__(256) void dinv_kernel(const int* __restrict__ cnt,
                                                   float* __restrict__ dinv, int N) {
    int i = blockIdx.x * blockDim.x + threadIdx.x;
    if (i < N) dinv[i] = rsqrtf((float)(cnt[i] + 1));
}

// ---------- node-count scan -> row_ptr, next ----------
__global__ __launch_bounds__(256) void scan_blocksums_kernel(const int* __restrict__ cnt,
                                                             int* __restrict__ bsum, int N) {
    __shared__ int tmp[256];
    int i = blockIdx.x * 256 + threadIdx.x;
    int v = (i < N) ? cnt[i] : 0;
    tmp[threadIdx.x] = v;
    __syncthreads();
    for (int off = 128; off > 0; off >>= 1) {
        if (threadIdx.x < off) tmp[threadIdx.x] += tmp[threadIdx.x + off];
        __syncthreads();
    }
    if (threadIdx.x == 0) bsum[blockIdx.x] = tmp[0];
}

__global__ __launch_bounds__(512) void scan_offsets_kernel(int* __restrict__ bsum, int nb,
                                                           int* __restrict__ row_ptr, int N) {
    __shared__ int tmp[512];
    int t = threadIdx.x;
    int v = (t < nb) ? bsum[t] : 0;
    tmp[t] = v;
    __syncthreads();
    for (int off = 1; off < 512; off <<= 1) {
        int a = (t >= off) ? tmp[t - off] : 0;
        __syncthreads();
        tmp[t] += a;
        __syncthreads();
    }
    if (t < nb) bsum[t] = tmp[t] - v;  // exclusive
    if (t == 0) row_ptr[N] = tmp[nb - 1];
}

__global__ __launch_bounds__(256) void scan_final_kernel(const int* __restrict__ cnt,
                                                         const int* __restrict__ bsum,
                                                         int* __restrict__ row_ptr,
                                                         int* __restrict__ next, int N) {
    __shared__ int tmp[256];
    int i = blockIdx.x * 256 + threadIdx.x;
    int v = (i < N) ? cnt[i] : 0;
    tmp[threadIdx.x] = v;
    __syncthreads();
    for (int off = 1; off < 256; off <<= 1) {
        int a = (threadIdx.x >= off) ? tmp[threadIdx.x - off] : 0;
        __syncthreads();
        tmp[threadIdx.x] += a;
        __syncthreads();
    }
    if (i < N) {
        int excl = tmp[threadIdx.x] - v + bsum[blockIdx.x];
        row_ptr[i] = excl;
        next[i] = excl;
    }
}

// ---------- bucket radix: count per (bucket, chunk) ----------
__global__ __launch_bounds__(256) void radix_count_kernel(const int* __restrict__ dst,
                                                          int* __restrict__ cmat,
                                                          long long E, int nbuck, int nblk) {
    __shared__ int h[256];
    int blk = blockIdx.x;
    for (int i = threadIdx.x; i < nbuck; i += 256) h[i] = 0;
    __syncthreads();
    long long e0 = (long long)blk * EPB;
    long long eend = e0 + EPB; if (eend > E) eend = E;
    for (long long e = e0 + threadIdx.x; e < eend; e += 256)
        atomicAdd(&h[dst[e] >> NPB_SHIFT], 1);
    __syncthreads();
    for (int i = threadIdx.x; i < nbuck; i += 256)
        cmat[(long long)i * nblk + blk] = h[i];
}

__global__ __launch_bounds__(256) void radix_btot_kernel(const int* __restrict__ cmat,
                                                         int* __restrict__ btot, int nblk) {
    __shared__ int tmp[256];
    long long row = (long long)blockIdx.x * nblk;
    int s = 0;
    for (int i = threadIdx.x; i < nblk; i += 256) s += cmat[row + i];
    tmp[threadIdx.x] = s;
    __syncthreads();
    for (int off = 128; off > 0; off >>= 1) {
        if (threadIdx.x < off) tmp[threadIdx.x] += tmp[threadIdx.x + off];
        __syncthreads();
    }
    if (threadIdx.x == 0) btot[blockIdx.x] = tmp[0];
}

__global__ __launch_bounds__(256) void radix_bscan_kernel(const int* __restrict__ btot,
                                                          int* __restrict__ bbase, int nbuck) {
    __shared__ int tmp[256];
    int t = threadIdx.x;
    int v = (t < nbuck) ? btot[t] : 0;
    tmp[t] = v;
    __syncthreads();
    for (int off = 1; off < 256; off <<= 1) {
        int a = (t >= off) ? tmp[t - off] : 0;
        __syncthreads();
        tmp[t] += a;
        __syncthreads();
    }
    if (t < nbuck) bbase[t] = tmp[t] - v;
}

__global__ __launch_bounds__(256) void radix_colscan_kernel(int* __restrict__ cmat,
                                                            const int* __restrict__ bbase,
                                                            int nblk) {
    __shared__ int tmp[256];
    __shared__ int carry;
    long long row = (long long)blockIdx.x * nblk;
    if (threadIdx.x == 0) carry = bbase[blockIdx.x];
    __syncthreads();
    for (int c0 = 0; c0 < nblk; c0 += 256) {
        int i = c0 + threadIdx.x;
        int v = (i < nblk) ? cmat[row + i] : 0;
        tmp[threadIdx.x] = v;
        __syncthreads();
        for (int off = 1; off < 256; off <<= 1) {
            int a = (threadIdx.x >= off) ? tmp[threadIdx.x - off] : 0;
            __syncthreads();
            tmp[threadIdx.x] += a;
            __syncthreads();
        }
        if (i < nblk) cmat[row + i] = tmp[threadIdx.x] - v + carry;
        __syncthreads();
        if (threadIdx.x == 0) carry += tmp[255];
        __syncthreads();
    }
}

__global__ __launch_bounds__(256) void radix_scatter_kernel(const int* __restrict__ src,
                                                            const int* __restrict__ dst,
                                                            const int* __restrict__ cmat,
                                                            int2* __restrict__ ebuf,
                                                            long long E, int nbuck, int nblk) {
    __shared__ int off[256];
    int blk = blockIdx.x;
    for (int i = threadIdx.x; i < nbuck; i += 256)
        off[i] = cmat[(long long)i * nblk + blk];
    __syncthreads();
    long long e0 = (long long)blk * EPB;
    long long eend = e0 + EPB; if (eend > E) eend = E;
    for (long long e = e0 + threadIdx.x; e < eend; e += 256) {
        int d = dst[e];
        int p = atomicAdd(&off[d >> NPB_SHIFT], 1);
        ebuf[p] = make_int2(src[e], d);
    }
}

// ---------- per-bucket LDS histogram from bucket-sorted ebuf ----------
__global__ __launch_bounds__(256) void bucket_hist_kernel(const int2* __restrict__ ebuf,
                                                          const int* __restrict__ bbase,
                                                          const int* __restrict__ btot,
                                                          int* __restrict__ cnt, int N) {
    __shared__ int h[1 << NPB_SHIFT];
    const int b = blockIdx.x / HSPLIT;
    const int part = blockIdx.x % HSPLIT;
    for (int i = threadIdx.x; i < (1 << NPB_SHIFT); i += 256) h[i] = 0;
    __syncthreads();
    const int e0 = bbase[b];
    const int tot = btot[b];
    const int per = (tot + HSPLIT - 1) / HSPLIT;
    int s0 = e0 + part * per;
    int s1 = s0 + per;
    const int eend = e0 + tot;
    if (s1 > eend) s1 = eend;
    const int base = b << NPB_SHIFT;
    for (int e = s0 + threadIdx.x; e < s1; e += 256)
        atomicAdd(&h[ebuf[e].y - base], 1);
    __syncthreads();
    int lim = N - base;
    if (lim > (1 << NPB_SHIFT)) lim = 1 << NPB_SHIFT;
    for (int i = threadIdx.x; i < lim; i += 256) {
        int v = h[i];
        if (v) atomicAdd(&cnt[base + i], v);
    }
}

__global__ __launch_bounds__(256) void radix_fill_kernel(const int2* __restrict__ ebuf,
                                                         int* __restrict__ next,
                                                         int* __restrict__ col,
                                                         long long E, int nchunks) {
    int g = blockIdx.x;
    int G = gridDim.x;
    int per = G >> 3;
    int c = (g & 7) * per + (g >> 3);
    if (c >= nchunks) return;
    long long e0 = (long long)c * EPB;
    long long eend = e0 + EPB; if (eend > E) eend = E;
    for (long long e = e0 + threadIdx.x; e < eend; e += 256) {
        int2 sd = ebuf[e];
        int p = atomicAdd(&next[sd.y], 1);
        col[p] = sd.x;
    }
}

// ---------- Y = X @ W (+ bias); output fp32 (Y) or bf16 (Yb) ----------
__global__ __launch_bounds__(256) void gemm128_kernel(const float* __restrict__ X,
                                                      const float* __restrict__ W,
                                                      const float* __restrict__ bias,
                                                      float* __restrict__ Y,
                                                      u16* __restrict__ Yb, int M) {
    __shared__ float sW[128 * 128];
    for (int i = threadIdx.x; i < 128 * 32; i += 256) {
        ((float4*)sW)[i] = ((const float4*)W)[i];
    }
    __syncthreads();

    const int lr = threadIdx.x >> 5;
    const int c4 = (threadIdx.x & 31) * 4;

    for (long long rg = blockIdx.x; rg * 8 < M; rg += gridDim.x) {
        long long row = rg * 8 + lr;
        if (row >= M) continue;
        const float4* xrow = (const float4*)(X + row * FEAT);
        float a0 = 0.f, a1 = 0.f, a2 = 0.f, a3 = 0.f;
#pragma unroll
        for (int k4 = 0; k4 < 32; ++k4) {
            float4 xv = xrow[k4];
            float4 w0 = *(const float4*)&sW[(4 * k4 + 0) * 128 + c4];
            float4 w1 = *(const float4*)&sW[(4 * k4 + 1) * 128 + c4];
            float4 w2 = *(const float4*)&sW[(4 * k4 + 2) * 128 + c4];
            float4 w3 = *(const float4*)&sW[(4 * k4 + 3) * 128 + c4];
            a0 += xv.x * w0.x + xv.y * w1.x + xv.z * w2.x + xv.w * w3.x;
            a1 += xv.x * w0.y + xv.y * w1.y + xv.z * w2.y + xv.w * w3.y;
            a2 += xv.x * w0.z + xv.y * w1.z + xv.z * w2.z + xv.w * w3.z;
            a3 += xv.x * w0.w + xv.y * w1.w + xv.z * w2.w + xv.w * w3.w;
        }
        if (bias) {
            a0 += bias[c4 + 0]; a1 += bias[c4 + 1];
            a2 += bias[c4 + 2]; a3 += bias[c4 + 3];
        }
        if (Yb) {
            ushort4 o;
            o.x = f2b(a0); o.y = f2b(a1); o.z = f2b(a2); o.w = f2b(a3);
            *(ushort4*)&Yb[row * FEAT + c4] = o;
        } else {
            float4 r; r.x = a0; r.y = a1; r.z = a2; r.w = a3;
            *(float4*)&Y[row * FEAT + c4] = r;
        }
    }
}

// ---------- gather-aggregate (bf16 P) + self-loop + bias + relu ----------
__global__ __launch_bounds__(256) void gather_kernel(const int* __restrict__ row_ptr,
                                                     const int* __restrict__ col,
                                                     const float* __restrict__ dinv,
                                                     const u16* __restrict__ Pb,
                                                     const float* __restrict__ bias,
                                                     float* __restrict__ OUT,
                                                     int N, int doRelu) {
    const int lane = threadIdx.x & 15;
    const int grp = threadIdx.x >> 4;  // 0..15
    const int n = blockIdx.x * 16 + grp;
    if (n >= N) return;

    const float di = dinv[n];
    const int f8 = lane * 8;

    uint4 sv = *(const uint4*)&Pb[(size_t)n * FEAT + f8];
    float a0 = bf_lo(sv.x) * di, a1 = bf_hi(sv.x) * di;
    float a2 = bf_lo(sv.y) * di, a3 = bf_hi(sv.y) * di;
    float a4 = bf_lo(sv.z) * di, a5 = bf_hi(sv.z) * di;
    float a6 = bf_lo(sv.w) * di, a7 = bf_hi(sv.w) * di;

    const int start = row_ptr[n];
    const int end = row_ptr[n + 1];

    for (int e0 = start; e0 < end; e0 += 16) {
        int mye = e0 + lane;
        int s = (mye < end) ? col[mye] : 0;
        float w = (mye < end) ? dinv[s] : 0.0f;
        int jmax = end - e0; if (jmax > 16) jmax = 16;
        int j = 0;
        for (; j + 3 < jmax; j += 4) {
            int s0 = __shfl(s, j, 16),     s1 = __shfl(s, j + 1, 16);
            int s2 = __shfl(s, j + 2, 16), s3 = __shfl(s, j + 3, 16);
            float w0 = __shfl(w, j, 16),     w1 = __shfl(w, j + 1, 16);
            float w2 = __shfl(w, j + 2, 16), w3 = __shfl(w, j + 3, 16);
            uint4 v0 = *(const uint4*)&Pb[(size_t)s0 * FEAT + f8];
            uint4 v1 = *(const uint4*)&Pb[(size_t)s1 * FEAT + f8];
            uint4 v2 = *(const uint4*)&Pb[(size_t)s2 * FEAT + f8];
            uint4 v3 = *(const uint4*)&Pb[(size_t)s3 * FEAT + f8];
            a0 += bf_lo(v0.x) * w0; a1 += bf_hi(v0.x) * w0;
            a2 += bf_lo(v0.y) * w0; a3 += bf_hi(v0.y) * w0;
            a4 += bf_lo(v0.z) * w0; a5 += bf_hi(v0.z) * w0;
            a6 += bf_lo(v0.w) * w0; a7 += bf_hi(v0.w) * w0;
            a0 += bf_lo(v1.x) * w1; a1 += bf_hi(v1.x) * w1;
            a2 += bf_lo(v1.y) * w1; a3 += bf_hi(v1.y) * w1;
            a4 += bf_lo(v1.z) * w1; a5 += bf_hi(v1.z) * w1;
            a6 += bf_lo(v1.w) * w1; a7 += bf_hi(v1.w) * w1;
            a0 += bf_lo(v2.x) * w2; a1 += bf_hi(v2.x) * w2;
            a2 += bf_lo(v2.y) * w2; a3 += bf_hi(v2.y) * w2;
            a4 += bf_lo(v2.z) * w2; a5 += bf_hi(v2.z) * w2;
            a6 += bf_lo(v2.w) * w2; a7 += bf_hi(v2.w) * w2;
            a0 += bf_lo(v3.x) * w3; a1 += bf_hi(v3.x) * w3;
            a2 += bf_lo(v3.y) * w3; a3 += bf_hi(v3.y) * w3;
            a4 += bf_lo(v3.z) * w3; a5 += bf_hi(v3.z) * w3;
            a6 += bf_lo(v3.w) * w3; a7 += bf_hi(v3.w) * w3;
        }
        for (; j < jmax; ++j) {
            int s0 = __shfl(s, j, 16);
            float w0 = __shfl(w, j, 16);
            uint4 v0 = *(const uint4*)&Pb[(size_t)s0 * FEAT + f8];
            a0 += bf_lo(v0.x) * w0; a1 += bf_hi(v0.x) * w0;
            a2 += bf_lo(v0.y) * w0; a3 += bf_hi(v0.y) * w0;
            a4 += bf_lo(v0.z) * w0; a5 += bf_hi(v0.z) * w0;
            a6 += bf_lo(v0.w) * w0; a7 += bf_hi(v0.w) * w0;
        }
    }

    const float4 b0 = *(const float4*)&bias[f8];
    const float4 b1 = *(const float4*)&bias[f8 + 4];
    float4 r0, r1;
    r0.x = a0 * di + b0.x; r0.y = a1 * di + b0.y;
    r0.z = a2 * di + b0.z; r0.w = a3 * di + b0.w;
    r1.x = a4 * di + b1.x; r1.y = a5 * di + b1.y;
    r1.z = a6 * di + b1.z; r1.w = a7 * di + b1.w;
    if (doRelu) {
        r0.x = fmaxf(r0.x, 0.f); r0.y = fmaxf(r0.y, 0.f);
        r0.z = fmaxf(r0.z, 0.f); r0.w = fmaxf(r0.w, 0.f);
        r1.x = fmaxf(r1.x, 0.f); r1.y = fmaxf(r1.y, 0.f);
        r1.z = fmaxf(r1.z, 0.f); r1.w = fmaxf(r1.w, 0.f);
    }
    *(float4*)&OUT[(size_t)n * FEAT + f8] = r0;
    *(float4*)&OUT[(size_t)n * FEAT + f8 + 4] = r1;
}

extern "C" void kernel_launch(void* const* d_in, const int* in_sizes, int n_in,
                              void* d_out, int out_size, void* d_ws, size_t ws_size,
                              hipStream_t stream) {
    const float* x  = (const float*)d_in[0];
    const int*   ei = (const int*)d_in[1];
    const float* W1 = (const float*)d_in[2];
    const float* b1 = (const float*)d_in[3];
    const float* W2 = (const float*)d_in[4];
    const float* b2 = (const float*)d_in[5];
    const float* Wl = (const float*)d_in[6];
    const float* bl = (const float*)d_in[7];
    float* out = (float*)d_out;

    const int N = in_sizes[0] / FEAT;      // 100000
    const long long E = in_sizes[1] / 2;   // 3200000
    const int* src = ei;
    const int* dst = ei + E;

    const int nb = (N + 255) / 256;
    const int nbuck = (N + (1 << NPB_SHIFT) - 1) >> NPB_SHIFT;  // 196
    const int nchunks = (int)((E + EPB - 1) / EPB);             // 782
    const int nblk = ((nchunks + 7) / 8) * 8;                   // 784

    // workspace layout (~92 MB)
    float* H       = (float*)d_ws;                     // N*128 f32 (aliases ebuf)
    u16*   Pb      = (u16*)(H + (long long)N * FEAT);  // N*128 bf16
    float* dinv    = (float*)(Pb + (long long)N * FEAT);
    int*   cnt     = (int*)(dinv + N);                 // N
    int*   row_ptr = cnt + N;                          // N+1
    int*   next    = row_ptr + N + 1;                  // N
    int*   bsum    = next + N;                         // 512
    int*   btot    = bsum + 512;                       // 256
    int*   bbase   = btot + 256;                       // 256
    int*   cmat    = bbase + 256;                      // nbuck*nblk
    int*   col     = cmat + (long long)nbuck * nblk;   // E
    int2*  ebuf    = (int2*)H;                         // E int2 (25.6MB, in H)

    // ---- bucket radix: sort edges by dst bucket ----
    radix_count_kernel<<<nblk, 256, 0, stream>>>(dst, cmat, E, nbuck, nblk);
    radix_btot_kernel<<<nbuck, 256, 0, stream>>>(cmat, btot, nblk);
    radix_bscan_kernel<<<1, 256, 0, stream>>>(btot, bbase, nbuck);
    radix_colscan_kernel<<<nbuck, 256, 0, stream>>>(cmat, bbase, nblk);
    radix_scatter_kernel<<<nblk, 256, 0, stream>>>(src, dst, cmat, ebuf, E, nbuck, nblk);

    // ---- degrees from bucket-sorted ebuf (LDS hist) ----
    hipMemsetAsync(cnt, 0, (size_t)N * sizeof(int), stream);
    bucket_hist_kernel<<<nbuck * HSPLIT, 256, 0, stream>>>(ebuf, bbase, btot, cnt, N);
    dinv_kernel<<<nb, 256, 0, stream>>>(cnt, dinv, N);
    scan_blocksums_kernel<<<nb, 256, 0, stream>>>(cnt, bsum, N);
    scan_offsets_kernel<<<1, 512, 0, stream>>>(bsum, nb, row_ptr, N);
    scan_final_kernel<<<nb, 256, 0, stream>>>(cnt, bsum, row_ptr, next, N);

    // ---- CSR fill ----
    radix_fill_kernel<<<nblk, 256, 0, stream>>>(ebuf, next, col, E, nchunks);

    const int gatherBlocks = (N + 15) / 16;

    // ---- layer 1 ---- (gemm writes Pb; ebuf consumed by fill before gather writes H)
    gemm128_kernel<<<2048, 256, 0, stream>>>(x, W1, nullptr, nullptr, Pb, N);
    gather_kernel<<<gatherBlocks, 256, 0, stream>>>(row_ptr, col, dinv, Pb, b1, H, N, 1);

    // ---- layer 2 ----
    gemm128_kernel<<<2048, 256, 0, stream>>>(H, W2, nullptr, nullptr, Pb, N);
    gather_kernel<<<gatherBlocks, 256, 0, stream>>>(row_ptr, col, dinv, Pb, b2, H, N, 1);

    // ---- output head ----
    gemm128_kernel<<<2048, 256, 0, stream>>>(H, Wl, bl, out, nullptr, N);
}

// Round 6
// 541.697 us; speedup vs baseline: 20.5863x; 1.1175x over previous
//
#include <hip/hip_runtime.h>
#include <hip/hip_bf16.h>

// GCN: h1 = relu(gcn(x, W1, b1)); h2 = relu(gcn(h1, W2, b2)); out = h2@Wl + bl
// gcn(x,W,b) = D^-1/2 (A+I) D^-1/2 (xW) + b, deg = in-degree(dst)+1
// Gather aggregation over per-call-built CSR (bucket-radix sort by dst>>9,
// then one block per bucket finishes hist/scan/fill entirely in LDS).
// P' = dinv[src] * (xW)[src] stored bf16 -> gather inner loop is a pure
// row-sum; final scale by dinv[dst] + bias + relu. Accumulation fp32.

#define FEAT 128
#define EPB 4096       // edges per radix chunk
#define NPB_SHIFT 9    // 512 nodes per bucket
#define NPB (1 << NPB_SHIFT)

typedef unsigned short u16;
typedef unsigned int u32;

static __device__ __forceinline__ float bf_lo(u32 u) { return __uint_as_float(u << 16); }
static __device__ __forceinline__ float bf_hi(u32 u) { return __uint_as_float(u & 0xffff0000u); }
static __device__ __forceinline__ u16 f2b(float f) {
    __hip_bfloat16 h = __float2bfloat16(f);
    return *reinterpret_cast<u16*>(&h);
}

// ---------- bucket radix: count per (bucket, chunk) ----------
__global__ __launch_bounds__(256) void radix_count_kernel(const int* __restrict__ dst,
                                                          int* __restrict__ cmat,
                                                          long long E, int nbuck, int nblk) {
    __shared__ int h[256];
    int blk = blockIdx.x;
    for (int i = threadIdx.x; i < nbuck; i += 256) h[i] = 0;
    __syncthreads();
    long long e0 = (long long)blk * EPB;
    long long eend = e0 + EPB; if (eend > E) eend = E;
    for (long long e = e0 + threadIdx.x; e < eend; e += 256)
        atomicAdd(&h[dst[e] >> NPB_SHIFT], 1);
    __syncthreads();
    for (int i = threadIdx.x; i < nbuck; i += 256)
        cmat[(long long)i * nblk + blk] = h[i];
}

__global__ __launch_bounds__(256) void radix_btot_kernel(const int* __restrict__ cmat,
                                                         int* __restrict__ btot, int nblk) {
    __shared__ int tmp[256];
    long long row = (long long)blockIdx.x * nblk;
    int s = 0;
    for (int i = threadIdx.x; i < nblk; i += 256) s += cmat[row + i];
    tmp[threadIdx.x] = s;
    __syncthreads();
    for (int off = 128; off > 0; off >>= 1) {
        if (threadIdx.x < off) tmp[threadIdx.x] += tmp[threadIdx.x + off];
        __syncthreads();
    }
    if (threadIdx.x == 0) btot[blockIdx.x] = tmp[0];
}

__global__ __launch_bounds__(256) void radix_bscan_kernel(const int* __restrict__ btot,
                                                          int* __restrict__ bbase, int nbuck) {
    __shared__ int tmp[256];
    int t = threadIdx.x;
    int v = (t < nbuck) ? btot[t] : 0;
    tmp[t] = v;
    __syncthreads();
    for (int off = 1; off < 256; off <<= 1) {
        int a = (t >= off) ? tmp[t - off] : 0;
        __syncthreads();
        tmp[t] += a;
        __syncthreads();
    }
    if (t < nbuck) bbase[t] = tmp[t] - v;
}

__global__ __launch_bounds__(256) void radix_colscan_kernel(int* __restrict__ cmat,
                                                            const int* __restrict__ bbase,
                                                            int nblk) {
    __shared__ int tmp[256];
    __shared__ int carry;
    long long row = (long long)blockIdx.x * nblk;
    if (threadIdx.x == 0) carry = bbase[blockIdx.x];
    __syncthreads();
    for (int c0 = 0; c0 < nblk; c0 += 256) {
        int i = c0 + threadIdx.x;
        int v = (i < nblk) ? cmat[row + i] : 0;
        tmp[threadIdx.x] = v;
        __syncthreads();
        for (int off = 1; off < 256; off <<= 1) {
            int a = (threadIdx.x >= off) ? tmp[threadIdx.x - off] : 0;
            __syncthreads();
            tmp[threadIdx.x] += a;
            __syncthreads();
        }
        if (i < nblk) cmat[row + i] = tmp[threadIdx.x] - v + carry;
        __syncthreads();
        if (threadIdx.x == 0) carry += tmp[255];
        __syncthreads();
    }
}

__global__ __launch_bounds__(256) void radix_scatter_kernel(const int* __restrict__ src,
                                                            const int* __restrict__ dst,
                                                            const int* __restrict__ cmat,
                                                            int2* __restrict__ ebuf,
                                                            long long E, int nbuck, int nblk) {
    __shared__ int off[256];
    int blk = blockIdx.x;
    for (int i = threadIdx.x; i < nbuck; i += 256)
        off[i] = cmat[(long long)i * nblk + blk];
    __syncthreads();
    long long e0 = (long long)blk * EPB;
    long long eend = e0 + EPB; if (eend > E) eend = E;
    for (long long e = e0 + threadIdx.x; e < eend; e += 256) {
        int d = dst[e];
        int p = atomicAdd(&off[d >> NPB_SHIFT], 1);
        ebuf[p] = make_int2(src[e], d);
    }
}

// ---------- per-bucket finisher: hist + scan + row_ptr/dinv + col fill ----------
// One 1024-thread block per bucket; everything in LDS, no global atomics.
__global__ __launch_bounds__(1024) void bucket_finish_kernel(const int2* __restrict__ ebuf,
                                                             const int* __restrict__ bbase,
                                                             const int* __restrict__ btot,
                                                             int* __restrict__ col,
                                                             int* __restrict__ row_ptr,
                                                             float* __restrict__ dinv,
                                                             int N, int nbuck, long long E) {
    __shared__ int hist[NPB];
    __shared__ int scn[NPB];
    const int tid = threadIdx.x;
    const int b = blockIdx.x;
    const int e0 = bbase[b];
    const int tot = btot[b];
    const int base = b << NPB_SHIFT;

    if (tid < NPB) hist[tid] = 0;
    __syncthreads();
    for (int e = e0 + tid; e < e0 + tot; e += 1024)
        atomicAdd(&hist[ebuf[e].y - base], 1);
    __syncthreads();

    // inclusive scan of hist -> scn
    if (tid < NPB) scn[tid] = hist[tid];
    __syncthreads();
    for (int off = 1; off < NPB; off <<= 1) {
        int a = 0;
        if (tid < NPB && tid >= off) a = scn[tid - off];
        __syncthreads();
        if (tid < NPB && tid >= off) scn[tid] += a;
        __syncthreads();
    }

    int lim = N - base; if (lim > NPB) lim = NPB;
    if (tid < lim) {
        int h = hist[tid];
        int excl = scn[tid] - h;
        row_ptr[base + tid] = e0 + excl;
        dinv[base + tid] = rsqrtf((float)(h + 1));
    }
    if (b == nbuck - 1 && tid == 0) row_ptr[N] = (int)E;
    __syncthreads();

    // repurpose hist as running offsets
    if (tid < NPB) hist[tid] = e0 + (scn[tid] - hist[tid]);
    __syncthreads();
    for (int e = e0 + tid; e < e0 + tot; e += 1024) {
        int2 sd = ebuf[e];
        int p = atomicAdd(&hist[sd.y - base], 1);
        col[p] = sd.x;
    }
}

// ---------- Y = X @ W (+ bias); optional row scale; fp32 (Y) or bf16 (Yb) out ----------
__global__ __launch_bounds__(256) void gemm128_kernel(const float* __restrict__ X,
                                                      const float* __restrict__ W,
                                                      const float* __restrict__ bias,
                                                      const float* __restrict__ scale,
                                                      float* __restrict__ Y,
                                                      u16* __restrict__ Yb, int M) {
    __shared__ float sW[128 * 128];
    for (int i = threadIdx.x; i < 128 * 32; i += 256) {
        ((float4*)sW)[i] = ((const float4*)W)[i];
    }
    __syncthreads();

    const int lr = threadIdx.x >> 5;
    const int c4 = (threadIdx.x & 31) * 4;

    for (long long rg = blockIdx.x; rg * 8 < M; rg += gridDim.x) {
        long long row = rg * 8 + lr;
        if (row >= M) continue;
        const float4* xrow = (const float4*)(X + row * FEAT);
        float a0 = 0.f, a1 = 0.f, a2 = 0.f, a3 = 0.f;
#pragma unroll
        for (int k4 = 0; k4 < 32; ++k4) {
            float4 xv = xrow[k4];
            float4 w0 = *(const float4*)&sW[(4 * k4 + 0) * 128 + c4];
            float4 w1 = *(const float4*)&sW[(4 * k4 + 1) * 128 + c4];
            float4 w2 = *(const float4*)&sW[(4 * k4 + 2) * 128 + c4];
            float4 w3 = *(const float4*)&sW[(4 * k4 + 3) * 128 + c4];
            a0 += xv.x * w0.x + xv.y * w1.x + xv.z * w2.x + xv.w * w3.x;
            a1 += xv.x * w0.y + xv.y * w1.y + xv.z * w2.y + xv.w * w3.y;
            a2 += xv.x * w0.z + xv.y * w1.z + xv.z * w2.z + xv.w * w3.z;
            a3 += xv.x * w0.w + xv.y * w1.w + xv.z * w2.w + xv.w * w3.w;
        }
        if (bias) {
            a0 += bias[c4 + 0]; a1 += bias[c4 + 1];
            a2 += bias[c4 + 2]; a3 += bias[c4 + 3];
        }
        if (Yb) {
            float sc = scale ? scale[row] : 1.0f;
            ushort4 o;
            o.x = f2b(a0 * sc); o.y = f2b(a1 * sc);
            o.z = f2b(a2 * sc); o.w = f2b(a3 * sc);
            *(ushort4*)&Yb[row * FEAT + c4] = o;
        } else {
            float4 r; r.x = a0; r.y = a1; r.z = a2; r.w = a3;
            *(float4*)&Y[row * FEAT + c4] = r;
        }
    }
}

// ---------- gather: OUT[n] = dinv[n]*(P'[n] + sum_{e:dst=n} P'[col[e]]) + bias ----------
// P' rows already carry dinv[src]. 16 lanes/row, 8 feats/lane (16B bf16 loads).
__global__ __launch_bounds__(256) void gather_kernel(const int* __restrict__ row_ptr,
                                                     const int* __restrict__ col,
                                                     const float* __restrict__ dinv,
                                                     const u16* __restrict__ Pb,
                                                     const float* __restrict__ bias,
                                                     float* __restrict__ OUT,
                                                     int N, int doRelu) {
    const int lane = threadIdx.x & 15;
    const int grp = threadIdx.x >> 4;  // 0..15
    const int n = blockIdx.x * 16 + grp;
    if (n >= N) return;

    const float di = dinv[n];
    const int f8 = lane * 8;

    // self-loop: P'[n] = dinv[n]*P[n]; final *di gives dinv^2*P[n]
    uint4 sv = *(const uint4*)&Pb[(size_t)n * FEAT + f8];
    float a0 = bf_lo(sv.x), a1 = bf_hi(sv.x);
    float a2 = bf_lo(sv.y), a3 = bf_hi(sv.y);
    float a4 = bf_lo(sv.z), a5 = bf_hi(sv.z);
    float a6 = bf_lo(sv.w), a7 = bf_hi(sv.w);

    const int start = row_ptr[n];
    const int end = row_ptr[n + 1];

    for (int e0 = start; e0 < end; e0 += 16) {
        int mye = e0 + lane;
        int s = (mye < end) ? col[mye] : -1;
        int jmax = end - e0; if (jmax > 16) jmax = 16;
        int j = 0;
        for (; j + 3 < jmax; j += 4) {
            int s0 = __shfl(s, j, 16),     s1 = __shfl(s, j + 1, 16);
            int s2 = __shfl(s, j + 2, 16), s3 = __shfl(s, j + 3, 16);
            uint4 v0 = *(const uint4*)&Pb[(size_t)s0 * FEAT + f8];
            uint4 v1 = *(const uint4*)&Pb[(size_t)s1 * FEAT + f8];
            uint4 v2 = *(const uint4*)&Pb[(size_t)s2 * FEAT + f8];
            uint4 v3 = *(const uint4*)&Pb[(size_t)s3 * FEAT + f8];
            a0 += bf_lo(v0.x); a1 += bf_hi(v0.x);
            a2 += bf_lo(v0.y); a3 += bf_hi(v0.y);
            a4 += bf_lo(v0.z); a5 += bf_hi(v0.z);
            a6 += bf_lo(v0.w); a7 += bf_hi(v0.w);
            a0 += bf_lo(v1.x); a1 += bf_hi(v1.x);
            a2 += bf_lo(v1.y); a3 += bf_hi(v1.y);
            a4 += bf_lo(v1.z); a5 += bf_hi(v1.z);
            a6 += bf_lo(v1.w); a7 += bf_hi(v1.w);
            a0 += bf_lo(v2.x); a1 += bf_hi(v2.x);
            a2 += bf_lo(v2.y); a3 += bf_hi(v2.y);
            a4 += bf_lo(v2.z); a5 += bf_hi(v2.z);
            a6 += bf_lo(v2.w); a7 += bf_hi(v2.w);
            a0 += bf_lo(v3.x); a1 += bf_hi(v3.x);
            a2 += bf_lo(v3.y); a3 += bf_hi(v3.y);
            a4 += bf_lo(v3.z); a5 += bf_hi(v3.z);
            a6 += bf_lo(v3.w); a7 += bf_hi(v3.w);
        }
        for (; j < jmax; ++j) {
            int s0 = __shfl(s, j, 16);
            uint4 v0 = *(const uint4*)&Pb[(size_t)s0 * FEAT + f8];
            a0 += bf_lo(v0.x); a1 += bf_hi(v0.x);
            a2 += bf_lo(v0.y); a3 += bf_hi(v0.y);
            a4 += bf_lo(v0.z); a5 += bf_hi(v0.z);
            a6 += bf_lo(v0.w); a7 += bf_hi(v0.w);
        }
    }

    const float4 b0 = *(const float4*)&bias[f8];
    const float4 b1 = *(const float4*)&bias[f8 + 4];
    float4 r0, r1;
    r0.x = a0 * di + b0.x; r0.y = a1 * di + b0.y;
    r0.z = a2 * di + b0.z; r0.w = a3 * di + b0.w;
    r1.x = a4 * di + b1.x; r1.y = a5 * di + b1.y;
    r1.z = a6 * di + b1.z; r1.w = a7 * di + b1.w;
    if (doRelu) {
        r0.x = fmaxf(r0.x, 0.f); r0.y = fmaxf(r0.y, 0.f);
        r0.z = fmaxf(r0.z, 0.f); r0.w = fmaxf(r0.w, 0.f);
        r1.x = fmaxf(r1.x, 0.f); r1.y = fmaxf(r1.y, 0.f);
        r1.z = fmaxf(r1.z, 0.f); r1.w = fmaxf(r1.w, 0.f);
    }
    *(float4*)&OUT[(size_t)n * FEAT + f8] = r0;
    *(float4*)&OUT[(size_t)n * FEAT + f8 + 4] = r1;
}

extern "C" void kernel_launch(void* const* d_in, const int* in_sizes, int n_in,
                              void* d_out, int out_size, void* d_ws, size_t ws_size,
                              hipStream_t stream) {
    const float* x  = (const float*)d_in[0];
    const int*   ei = (const int*)d_in[1];
    const float* W1 = (const float*)d_in[2];
    const float* b1 = (const float*)d_in[3];
    const float* W2 = (const float*)d_in[4];
    const float* b2 = (const float*)d_in[5];
    const float* Wl = (const float*)d_in[6];
    const float* bl = (const float*)d_in[7];
    float* out = (float*)d_out;

    const int N = in_sizes[0] / FEAT;      // 100000
    const long long E = in_sizes[1] / 2;   // 3200000
    const int* src = ei;
    const int* dst = ei + E;

    const int nbuck = (N + NPB - 1) >> NPB_SHIFT;    // 196
    const int nchunks = (int)((E + EPB - 1) / EPB);  // 782
    const int nblk = ((nchunks + 7) / 8) * 8;        // 784

    // workspace layout (~91 MB)
    float* H       = (float*)d_ws;                     // N*128 f32 (aliases ebuf)
    u16*   Pb      = (u16*)(H + (long long)N * FEAT);  // N*128 bf16
    float* dinv    = (float*)(Pb + (long long)N * FEAT);
    int*   row_ptr = (int*)(dinv + N);                 // N+1
    int*   btot    = row_ptr + N + 1;                  // 256
    int*   bbase   = btot + 256;                       // 256
    int*   cmat    = bbase + 256;                      // nbuck*nblk
    int*   col     = cmat + (long long)nbuck * nblk;   // E
    int2*  ebuf    = (int2*)H;                         // E int2 (25.6MB, in H)

    // ---- bucket radix: sort edges by dst bucket ----
    radix_count_kernel<<<nblk, 256, 0, stream>>>(dst, cmat, E, nbuck, nblk);
    radix_btot_kernel<<<nbuck, 256, 0, stream>>>(cmat, btot, nblk);
    radix_bscan_kernel<<<1, 256, 0, stream>>>(btot, bbase, nbuck);
    radix_colscan_kernel<<<nbuck, 256, 0, stream>>>(cmat, bbase, nblk);
    radix_scatter_kernel<<<nblk, 256, 0, stream>>>(src, dst, cmat, ebuf, E, nbuck, nblk);

    // ---- per-bucket finisher: row_ptr, dinv, col ----
    bucket_finish_kernel<<<nbuck, 1024, 0, stream>>>(ebuf, bbase, btot, col, row_ptr,
                                                     dinv, N, nbuck, E);

    const int gatherBlocks = (N + 15) / 16;

    // ---- layer 1 ---- (P' = dinv * xW1, bf16; ebuf consumed before gather writes H)
    gemm128_kernel<<<2048, 256, 0, stream>>>(x, W1, nullptr, dinv, nullptr, Pb, N);
    gather_kernel<<<gatherBlocks, 256, 0, stream>>>(row_ptr, col, dinv, Pb, b1, H, N, 1);

    // ---- layer 2 ----
    gemm128_kernel<<<2048, 256, 0, stream>>>(H, W2, nullptr, dinv, nullptr, Pb, N);
    gather_kernel<<<gatherBlocks, 256, 0, stream>>>(row_ptr, col, dinv, Pb, b2, H, N, 1);

    // ---- output head ----
    gemm128_kernel<<<2048, 256, 0, stream>>>(H, Wl, bl, nullptr, out, nullptr, N);
}

// Round 7
// 440.319 us; speedup vs baseline: 25.3261x; 1.2302x over previous
//
#include <hip/hip_runtime.h>
#include <hip/hip_bf16.h>
#include <hip/hip_fp16.h>

// GCN: h1 = relu(gcn(x, W1, b1)); h2 = relu(gcn(h1, W2, b2)); out = h2@Wl + bl
// gcn(x,W,b) = D^-1/2 (A+I) D^-1/2 (xW) + b, deg = in-degree(dst)+1
// CSR built per call (bucket radix by dst>>9 + per-bucket LDS finisher).
// All three GEMMs use v_mfma_f32_16x16x32_f16 (fp16 in, fp32 accum).
// P' = dinv*(xW) and hidden states stored fp16; aggregation accumulates fp32.

#define FEAT 128
#define EPB 4096       // edges per radix chunk
#define NPB_SHIFT 9    // 512 nodes per bucket
#define NPB (1 << NPB_SHIFT)

typedef unsigned short u16;
typedef unsigned int u32;
typedef _Float16 f16;
typedef __attribute__((ext_vector_type(8))) _Float16 f16x8;
typedef __attribute__((ext_vector_type(4))) float f32x4;

static __device__ __forceinline__ u16 f2h(float f) {
    f16 h = (f16)f;
    return *reinterpret_cast<u16*>(&h);
}

// ---------- bucket radix: count per (bucket, chunk) ----------
__global__ __launch_bounds__(256) void radix_count_kernel(const int* __restrict__ dst,
                                                          int* __restrict__ cmat,
                                                          long long E, int nbuck, int nblk) {
    __shared__ int h[256];
    int blk = blockIdx.x;
    for (int i = threadIdx.x; i < nbuck; i += 256) h[i] = 0;
    __syncthreads();
    long long e0 = (long long)blk * EPB;
    long long eend = e0 + EPB; if (eend > E) eend = E;
    for (long long e = e0 + threadIdx.x; e < eend; e += 256)
        atomicAdd(&h[dst[e] >> NPB_SHIFT], 1);
    __syncthreads();
    for (int i = threadIdx.x; i < nbuck; i += 256)
        cmat[(long long)i * nblk + blk] = h[i];
}

__global__ __launch_bounds__(256) void radix_btot_kernel(const int* __restrict__ cmat,
                                                         int* __restrict__ btot, int nblk) {
    __shared__ int tmp[256];
    long long row = (long long)blockIdx.x * nblk;
    int s = 0;
    for (int i = threadIdx.x; i < nblk; i += 256) s += cmat[row + i];
    tmp[threadIdx.x] = s;
    __syncthreads();
    for (int off = 128; off > 0; off >>= 1) {
        if (threadIdx.x < off) tmp[threadIdx.x] += tmp[threadIdx.x + off];
        __syncthreads();
    }
    if (threadIdx.x == 0) btot[blockIdx.x] = tmp[0];
}

__global__ __launch_bounds__(256) void radix_bscan_kernel(const int* __restrict__ btot,
                                                          int* __restrict__ bbase, int nbuck) {
    __shared__ int tmp[256];
    int t = threadIdx.x;
    int v = (t < nbuck) ? btot[t] : 0;
    tmp[t] = v;
    __syncthreads();
    for (int off = 1; off < 256; off <<= 1) {
        int a = (t >= off) ? tmp[t - off] : 0;
        __syncthreads();
        tmp[t] += a;
        __syncthreads();
    }
    if (t < nbuck) bbase[t] = tmp[t] - v;
}

__global__ __launch_bounds__(256) void radix_colscan_kernel(int* __restrict__ cmat,
                                                            const int* __restrict__ bbase,
                                                            int nblk) {
    __shared__ int tmp[256];
    __shared__ int carry;
    long long row = (long long)blockIdx.x * nblk;
    if (threadIdx.x == 0) carry = bbase[blockIdx.x];
    __syncthreads();
    for (int c0 = 0; c0 < nblk; c0 += 256) {
        int i = c0 + threadIdx.x;
        int v = (i < nblk) ? cmat[row + i] : 0;
        tmp[threadIdx.x] = v;
        __syncthreads();
        for (int off = 1; off < 256; off <<= 1) {
            int a = (threadIdx.x >= off) ? tmp[threadIdx.x - off] : 0;
            __syncthreads();
            tmp[threadIdx.x] += a;
            __syncthreads();
        }
        if (i < nblk) cmat[row + i] = tmp[threadIdx.x] - v + carry;
        __syncthreads();
        if (threadIdx.x == 0) carry += tmp[255];
        __syncthreads();
    }
}

__global__ __launch_bounds__(256) void radix_scatter_kernel(const int* __restrict__ src,
                                                            const int* __restrict__ dst,
                                                            const int* __restrict__ cmat,
                                                            int2* __restrict__ ebuf,
                                                            long long E, int nbuck, int nblk) {
    __shared__ int off[256];
    int blk = blockIdx.x;
    for (int i = threadIdx.x; i < nbuck; i += 256)
        off[i] = cmat[(long long)i * nblk + blk];
    __syncthreads();
    long long e0 = (long long)blk * EPB;
    long long eend = e0 + EPB; if (eend > E) eend = E;
    for (long long e = e0 + threadIdx.x; e < eend; e += 256) {
        int d = dst[e];
        int p = atomicAdd(&off[d >> NPB_SHIFT], 1);
        ebuf[p] = make_int2(src[e], d);
    }
}

// ---------- per-bucket finisher: hist + scan + row_ptr/dinv + col fill ----------
__global__ __launch_bounds__(1024) void bucket_finish_kernel(const int2* __restrict__ ebuf,
                                                             const int* __restrict__ bbase,
                                                             const int* __restrict__ btot,
                                                             int* __restrict__ col,
                                                             int* __restrict__ row_ptr,
                                                             float* __restrict__ dinv,
                                                             int N, int nbuck, long long E) {
    __shared__ int hist[NPB];
    __shared__ int scn[NPB];
    const int tid = threadIdx.x;
    const int b = blockIdx.x;
    const int e0 = bbase[b];
    const int tot = btot[b];
    const int base = b << NPB_SHIFT;

    if (tid < NPB) hist[tid] = 0;
    __syncthreads();
    for (int e = e0 + tid; e < e0 + tot; e += 1024)
        atomicAdd(&hist[ebuf[e].y - base], 1);
    __syncthreads();

    if (tid < NPB) scn[tid] = hist[tid];
    __syncthreads();
    for (int off = 1; off < NPB; off <<= 1) {
        int a = 0;
        if (tid < NPB && tid >= off) a = scn[tid - off];
        __syncthreads();
        if (tid < NPB && tid >= off) scn[tid] += a;
        __syncthreads();
    }

    int lim = N - base; if (lim > NPB) lim = NPB;
    if (tid < lim) {
        int h = hist[tid];
        int excl = scn[tid] - h;
        row_ptr[base + tid] = e0 + excl;
        dinv[base + tid] = rsqrtf((float)(h + 1));
    }
    if (b == nbuck - 1 && tid == 0) row_ptr[N] = (int)E;
    __syncthreads();

    if (tid < NPB) hist[tid] = e0 + (scn[tid] - hist[tid]);
    __syncthreads();
    for (int e = e0 + tid; e < e0 + tot; e += 1024) {
        int2 sd = ebuf[e];
        int p = atomicAdd(&hist[sd.y - base], 1);
        col[p] = sd.x;
    }
}

// ---------- fp32 -> fp16 convert (8 elems/thread) ----------
__global__ __launch_bounds__(256) void f32_to_f16_kernel(const float* __restrict__ in,
                                                         u16* __restrict__ out, long long n8) {
    for (long long i = (long long)blockIdx.x * blockDim.x + threadIdx.x; i < n8;
         i += (long long)gridDim.x * blockDim.x) {
        float4 v0 = ((const float4*)in)[i * 2];
        float4 v1 = ((const float4*)in)[i * 2 + 1];
        ushort4 o0, o1;
        o0.x = f2h(v0.x); o0.y = f2h(v0.y); o0.z = f2h(v0.z); o0.w = f2h(v0.w);
        o1.x = f2h(v1.x); o1.y = f2h(v1.y); o1.z = f2h(v1.z); o1.w = f2h(v1.w);
        ((ushort4*)out)[i * 2] = o0;
        ((ushort4*)out)[i * 2 + 1] = o1;
    }
}

// ---------- prepack W (128x128 f32, row-major k x n) into MFMA B-frag order ----------
// Wf[((kk*8+nb)*64+lane)*8+j] = fp16(W[(kk*32+(lane>>4)*8+j)*128 + nb*16+(lane&15)])
__global__ __launch_bounds__(256) void prepack_w_kernel(const float* __restrict__ W,
                                                        u16* __restrict__ Wf) {
    for (int i = threadIdx.x; i < 16384; i += 256) {
        int j = i & 7;
        int lane = (i >> 3) & 63;
        int nb = (i >> 9) & 7;
        int kk = i >> 12;
        int k = kk * 32 + (lane >> 4) * 8 + j;
        int n = nb * 16 + (lane & 15);
        Wf[i] = f2h(W[k * 128 + n]);
    }
}

// ---------- MFMA GEMM: Y[M,128] = A[M,128](f16) @ W(prepacked f16) ----------
// 4 waves/block, 32-row strip per wave. Epilogue: +bias, *scale(row),
// output fp16 (Yh) or fp32 (Yf).
__global__ __launch_bounds__(256) void mfma_gemm_kernel(const u16* __restrict__ A,
                                                        const u16* __restrict__ Wf,
                                                        const float* __restrict__ bias,
                                                        const float* __restrict__ scale,
                                                        u16* __restrict__ Yh,
                                                        float* __restrict__ Yf, int M) {
    __shared__ u16 sB[4 * 8 * 64 * 8];  // 32 KB
    for (int i = threadIdx.x; i < 2048; i += 256)
        ((uint4*)sB)[i] = ((const uint4*)Wf)[i];
    __syncthreads();

    const int wid = threadIdx.x >> 6;
    const int lane = threadIdx.x & 63;
    const int lrow = lane & 15;
    const int lkb = lane >> 4;

    const int nstrip = (M + 31) / 32;
    for (int strip = blockIdx.x * 4 + wid; strip < nstrip; strip += gridDim.x * 4) {
        const int row0 = strip * 32;
        f16x8 a[2][4];
#pragma unroll
        for (int t = 0; t < 2; ++t)
#pragma unroll
            for (int kk = 0; kk < 4; ++kk)
                a[t][kk] = *(const f16x8*)&A[(size_t)(row0 + t * 16 + lrow) * FEAT +
                                            kk * 32 + lkb * 8];
        f32x4 acc[2][8];
#pragma unroll
        for (int t = 0; t < 2; ++t)
#pragma unroll
            for (int nb = 0; nb < 8; ++nb) {
                acc[t][nb][0] = 0.f; acc[t][nb][1] = 0.f;
                acc[t][nb][2] = 0.f; acc[t][nb][3] = 0.f;
            }
#pragma unroll
        for (int kk = 0; kk < 4; ++kk)
#pragma unroll
            for (int nb = 0; nb < 8; ++nb) {
                f16x8 b = *(const f16x8*)&sB[((kk * 8 + nb) * 64 + lane) * 8];
                acc[0][nb] = __builtin_amdgcn_mfma_f32_16x16x32_f16(a[0][kk], b, acc[0][nb], 0, 0, 0);
                acc[1][nb] = __builtin_amdgcn_mfma_f32_16x16x32_f16(a[1][kk], b, acc[1][nb], 0, 0, 0);
            }
        // epilogue: C mapping col = lane&15, row = (lane>>4)*4 + r
#pragma unroll
        for (int t = 0; t < 2; ++t) {
#pragma unroll
            for (int nb = 0; nb < 8; ++nb) {
#pragma unroll
                for (int r = 0; r < 4; ++r) {
                    int row = row0 + t * 16 + (lane >> 4) * 4 + r;
                    int c = nb * 16 + (lane & 15);
                    float v = acc[t][nb][r];
                    if (bias) v += bias[c];
                    if (scale) v *= scale[row];
                    if (Yh) Yh[(size_t)row * FEAT + c] = f2h(v);
                    else    Yf[(size_t)row * FEAT + c] = v;
                }
            }
        }
    }
}

// ---------- gather: OUT[n] = relu(dinv[n]*(P'[n] + sum P'[col[e]]) + bias), fp16 out ----------
__global__ __launch_bounds__(256) void gather_kernel(const int* __restrict__ row_ptr,
                                                     const int* __restrict__ col,
                                                     const float* __restrict__ dinv,
                                                     const u16* __restrict__ Pb,
                                                     const float* __restrict__ bias,
                                                     u16* __restrict__ OUT,
                                                     int N, int doRelu) {
    const int lane = threadIdx.x & 15;
    const int grp = threadIdx.x >> 4;  // 0..15
    const int n = blockIdx.x * 16 + grp;
    if (n >= N) return;

    const float di = dinv[n];
    const int f8 = lane * 8;

    float a0, a1, a2, a3, a4, a5, a6, a7;
    {
        uint4 sv = *(const uint4*)&Pb[(size_t)n * FEAT + f8];
        float2 f0 = __half22float2(*(__half2*)&sv.x);
        float2 f1 = __half22float2(*(__half2*)&sv.y);
        float2 f2 = __half22float2(*(__half2*)&sv.z);
        float2 f3 = __half22float2(*(__half2*)&sv.w);
        a0 = f0.x; a1 = f0.y; a2 = f1.x; a3 = f1.y;
        a4 = f2.x; a5 = f2.y; a6 = f3.x; a7 = f3.y;
    }

#define ACC8(v) { \
        float2 f0 = __half22float2(*(__half2*)&(v).x); \
        float2 f1 = __half22float2(*(__half2*)&(v).y); \
        float2 f2 = __half22float2(*(__half2*)&(v).z); \
        float2 f3 = __half22float2(*(__half2*)&(v).w); \
        a0 += f0.x; a1 += f0.y; a2 += f1.x; a3 += f1.y; \
        a4 += f2.x; a5 += f2.y; a6 += f3.x; a7 += f3.y; }

    const int start = row_ptr[n];
    const int end = row_ptr[n + 1];

    for (int e0 = start; e0 < end; e0 += 16) {
        int mye = e0 + lane;
        int s = (mye < end) ? col[mye] : -1;
        int jmax = end - e0; if (jmax > 16) jmax = 16;
        int j = 0;
        for (; j + 3 < jmax; j += 4) {
            int s0 = __shfl(s, j, 16),     s1 = __shfl(s, j + 1, 16);
            int s2 = __shfl(s, j + 2, 16), s3 = __shfl(s, j + 3, 16);
            uint4 v0 = *(const uint4*)&Pb[(size_t)s0 * FEAT + f8];
            uint4 v1 = *(const uint4*)&Pb[(size_t)s1 * FEAT + f8];
            uint4 v2 = *(const uint4*)&Pb[(size_t)s2 * FEAT + f8];
            uint4 v3 = *(const uint4*)&Pb[(size_t)s3 * FEAT + f8];
            ACC8(v0); ACC8(v1); ACC8(v2); ACC8(v3);
        }
        for (; j < jmax; ++j) {
            int s0 = __shfl(s, j, 16);
            uint4 v0 = *(const uint4*)&Pb[(size_t)s0 * FEAT + f8];
            ACC8(v0);
        }
    }
#undef ACC8

    const float4 b0 = *(const float4*)&bias[f8];
    const float4 b1 = *(const float4*)&bias[f8 + 4];
    float r0 = a0 * di + b0.x, r1 = a1 * di + b0.y;
    float r2 = a2 * di + b0.z, r3 = a3 * di + b0.w;
    float r4 = a4 * di + b1.x, r5 = a5 * di + b1.y;
    float r6 = a6 * di + b1.z, r7 = a7 * di + b1.w;
    if (doRelu) {
        r0 = fmaxf(r0, 0.f); r1 = fmaxf(r1, 0.f); r2 = fmaxf(r2, 0.f); r3 = fmaxf(r3, 0.f);
        r4 = fmaxf(r4, 0.f); r5 = fmaxf(r5, 0.f); r6 = fmaxf(r6, 0.f); r7 = fmaxf(r7, 0.f);
    }
    ushort4 o0, o1;
    o0.x = f2h(r0); o0.y = f2h(r1); o0.z = f2h(r2); o0.w = f2h(r3);
    o1.x = f2h(r4); o1.y = f2h(r5); o1.z = f2h(r6); o1.w = f2h(r7);
    *(ushort4*)&OUT[(size_t)n * FEAT + f8] = o0;
    *(ushort4*)&OUT[(size_t)n * FEAT + f8 + 4] = o1;
}

extern "C" void kernel_launch(void* const* d_in, const int* in_sizes, int n_in,
                              void* d_out, int out_size, void* d_ws, size_t ws_size,
                              hipStream_t stream) {
    const float* x  = (const float*)d_in[0];
    const int*   ei = (const int*)d_in[1];
    const float* W1 = (const float*)d_in[2];
    const float* b1 = (const float*)d_in[3];
    const float* W2 = (const float*)d_in[4];
    const float* b2 = (const float*)d_in[5];
    const float* Wl = (const float*)d_in[6];
    const float* bl = (const float*)d_in[7];
    float* out = (float*)d_out;

    const int N = in_sizes[0] / FEAT;      // 100000
    const long long E = in_sizes[1] / 2;   // 3200000
    const int* src = ei;
    const int* dst = ei + E;

    const int nbuck = (N + NPB - 1) >> NPB_SHIFT;    // 196
    const int nchunks = (int)((E + EPB - 1) / EPB);  // 782
    const int nblk = ((nchunks + 7) / 8) * 8;        // 784

    // workspace layout (~91 MB)
    u16*   H       = (u16*)d_ws;                       // N*128 fp16 (aliases ebuf)
    u16*   Xh      = H + (long long)N * FEAT;          // N*128 fp16
    u16*   Pb      = Xh + (long long)N * FEAT;         // N*128 fp16
    float* dinv    = (float*)(Pb + (long long)N * FEAT);
    int*   row_ptr = (int*)(dinv + N);                 // N+1
    int*   btot    = row_ptr + N + 1;                  // 256
    int*   bbase   = btot + 256;                       // 256
    int*   cmat    = bbase + 256;                      // nbuck*nblk
    u16*   Wf1     = (u16*)(cmat + (long long)nbuck * nblk);  // 16384
    u16*   Wf2     = Wf1 + 16384;
    u16*   Wfl     = Wf2 + 16384;
    int*   col     = (int*)(Wfl + 16384);              // E
    int2*  ebuf    = (int2*)H;                         // E int2 (25.6MB)

    // ---- bucket radix: sort edges by dst bucket ----
    radix_count_kernel<<<nblk, 256, 0, stream>>>(dst, cmat, E, nbuck, nblk);
    radix_btot_kernel<<<nbuck, 256, 0, stream>>>(cmat, btot, nblk);
    radix_bscan_kernel<<<1, 256, 0, stream>>>(btot, bbase, nbuck);
    radix_colscan_kernel<<<nbuck, 256, 0, stream>>>(cmat, bbase, nblk);
    radix_scatter_kernel<<<nblk, 256, 0, stream>>>(src, dst, cmat, ebuf, E, nbuck, nblk);

    // ---- per-bucket finisher: row_ptr, dinv, col (consumes ebuf) ----
    bucket_finish_kernel<<<nbuck, 1024, 0, stream>>>(ebuf, bbase, btot, col, row_ptr,
                                                     dinv, N, nbuck, E);

    // ---- fp16 conversions / weight prepack ----
    f32_to_f16_kernel<<<2048, 256, 0, stream>>>(x, Xh, (long long)N * FEAT / 8);
    prepack_w_kernel<<<1, 256, 0, stream>>>(W1, Wf1);
    prepack_w_kernel<<<1, 256, 0, stream>>>(W2, Wf2);
    prepack_w_kernel<<<1, 256, 0, stream>>>(Wl, Wfl);

    const int gemmGrid = ((N + 31) / 32 + 3) / 4;
    const int gatherBlocks = (N + 15) / 16;

    // ---- layer 1: P' = dinv * (x @ W1), fp16 ----
    mfma_gemm_kernel<<<gemmGrid, 256, 0, stream>>>(Xh, Wf1, nullptr, dinv, Pb, nullptr, N);
    gather_kernel<<<gatherBlocks, 256, 0, stream>>>(row_ptr, col, dinv, Pb, b1, H, N, 1);

    // ---- layer 2 ----
    mfma_gemm_kernel<<<gemmGrid, 256, 0, stream>>>(H, Wf2, nullptr, dinv, Pb, nullptr, N);
    gather_kernel<<<gatherBlocks, 256, 0, stream>>>(row_ptr, col, dinv, Pb, b2, H, N, 1);

    // ---- output head: out = h2 @ Wl + bl (fp32) ----
    mfma_gemm_kernel<<<gemmGrid, 256, 0, stream>>>(H, Wfl, bl, nullptr, nullptr, out, N);
}

// Round 8
// 413.907 us; speedup vs baseline: 26.9422x; 1.0638x over previous
//
#include <hip/hip_runtime.h>
#include <hip/hip_bf16.h>
#include <hip/hip_fp16.h>

// GCN: h1 = relu(gcn(x, W1, b1)); h2 = relu(gcn(h1, W2, b2)); out = h2@Wl + bl
// gcn(x,W,b) = D^-1/2 (A+I) D^-1/2 (xW) + b, deg = in-degree(dst)+1
// CSR built per call: bucket radix by dst>>9 (scatter uses block-local LDS
// counting sort -> coalesced run writes), per-bucket LDS finisher.
// GEMMs: v_mfma_f32_16x16x32_f16 (fp16 in, fp32 accum); layer-1 GEMM fuses
// the fp32->fp16 conversion of x. P' = dinv*(xW) and hidden states fp16.

#define FEAT 128
#define EPB 4096       // edges per radix chunk
#define NPB_SHIFT 9    // 512 nodes per bucket
#define NPB (1 << NPB_SHIFT)

typedef unsigned short u16;
typedef unsigned int u32;
typedef _Float16 f16;
typedef __attribute__((ext_vector_type(8))) _Float16 f16x8;
typedef __attribute__((ext_vector_type(4))) float f32x4;

static __device__ __forceinline__ u16 f2h(float f) {
    f16 h = (f16)f;
    return *reinterpret_cast<u16*>(&h);
}

// ---------- bucket radix: count per (bucket, chunk) ----------
__global__ __launch_bounds__(256) void radix_count_kernel(const int* __restrict__ dst,
                                                          int* __restrict__ cmat,
                                                          long long E, int nbuck, int nblk) {
    __shared__ int h[256];
    int blk = blockIdx.x;
    for (int i = threadIdx.x; i < nbuck; i += 256) h[i] = 0;
    __syncthreads();
    long long e0 = (long long)blk * EPB;
    long long eend = e0 + EPB; if (eend > E) eend = E;
    for (long long e = e0 + threadIdx.x; e < eend; e += 256)
        atomicAdd(&h[dst[e] >> NPB_SHIFT], 1);
    __syncthreads();
    for (int i = threadIdx.x; i < nbuck; i += 256)
        cmat[(long long)i * nblk + blk] = h[i];
}

__global__ __launch_bounds__(256) void radix_btot_kernel(const int* __restrict__ cmat,
                                                         int* __restrict__ btot, int nblk) {
    __shared__ int tmp[256];
    long long row = (long long)blockIdx.x * nblk;
    int s = 0;
    for (int i = threadIdx.x; i < nblk; i += 256) s += cmat[row + i];
    tmp[threadIdx.x] = s;
    __syncthreads();
    for (int off = 128; off > 0; off >>= 1) {
        if (threadIdx.x < off) tmp[threadIdx.x] += tmp[threadIdx.x + off];
        __syncthreads();
    }
    if (threadIdx.x == 0) btot[blockIdx.x] = tmp[0];
}

__global__ __launch_bounds__(256) void radix_bscan_kernel(const int* __restrict__ btot,
                                                          int* __restrict__ bbase, int nbuck) {
    __shared__ int tmp[256];
    int t = threadIdx.x;
    int v = (t < nbuck) ? btot[t] : 0;
    tmp[t] = v;
    __syncthreads();
    for (int off = 1; off < 256; off <<= 1) {
        int a = (t >= off) ? tmp[t - off] : 0;
        __syncthreads();
        tmp[t] += a;
        __syncthreads();
    }
    if (t < nbuck) bbase[t] = tmp[t] - v;
}

__global__ __launch_bounds__(256) void radix_colscan_kernel(int* __restrict__ cmat,
                                                            const int* __restrict__ bbase,
                                                            int nblk) {
    __shared__ int tmp[256];
    __shared__ int carry;
    long long row = (long long)blockIdx.x * nblk;
    if (threadIdx.x == 0) carry = bbase[blockIdx.x];
    __syncthreads();
    for (int c0 = 0; c0 < nblk; c0 += 256) {
        int i = c0 + threadIdx.x;
        int v = (i < nblk) ? cmat[row + i] : 0;
        tmp[threadIdx.x] = v;
        __syncthreads();
        for (int off = 1; off < 256; off <<= 1) {
            int a = (threadIdx.x >= off) ? tmp[threadIdx.x - off] : 0;
            __syncthreads();
            tmp[threadIdx.x] += a;
            __syncthreads();
        }
        if (i < nblk) cmat[row + i] = tmp[threadIdx.x] - v + carry;
        __syncthreads();
        if (threadIdx.x == 0) carry += tmp[255];
        __syncthreads();
    }
}

// ---------- scatter with block-local counting sort; coalesced run writes ----------
// After colscan, cmat is globally monotone, so local count(b,blk) = next - base.
__global__ __launch_bounds__(256) void radix_scatter_kernel(const int* __restrict__ src,
                                                            const int* __restrict__ dst,
                                                            const int* __restrict__ cmat,
                                                            int2* __restrict__ ebuf,
                                                            long long E, int nbuck, int nblk) {
    __shared__ int gbase[256];
    __shared__ int lbase[256];
    __shared__ int lofs[256];
    __shared__ u16 bslot[EPB];
    __shared__ int2 sorted[EPB];
    const int blk = blockIdx.x;
    const int tid = threadIdx.x;
    long long e0 = (long long)blk * EPB;
    if (e0 >= E) return;
    const int cnt = (int)((E - e0 < EPB) ? (E - e0) : EPB);

    // local per-bucket count from cmat differences
    int v = 0;
    if (tid < nbuck) {
        int base = cmat[(long long)tid * nblk + blk];
        int nxt;
        if (blk + 1 < nblk) nxt = cmat[(long long)tid * nblk + blk + 1];
        else nxt = (tid + 1 < nbuck) ? cmat[(long long)(tid + 1) * nblk] : (int)E;
        gbase[tid] = base;
        v = nxt - base;
    }
    lbase[tid] = v;
    lofs[tid] = v;   // stash own count
    __syncthreads();
    for (int off = 1; off < 256; off <<= 1) {
        int a = (tid >= off) ? lbase[tid - off] : 0;
        __syncthreads();
        lbase[tid] += a;
        __syncthreads();
    }
    int excl = lbase[tid] - lofs[tid];
    __syncthreads();
    lbase[tid] = excl;
    lofs[tid] = excl;
    __syncthreads();

    // stage bucket-sorted edges in LDS
    for (int i = tid; i < cnt; i += 256) {
        int d = dst[e0 + i];
        int b = d >> NPB_SHIFT;
        int p = atomicAdd(&lofs[b], 1);
        sorted[p] = make_int2(src[e0 + i], d);
        bslot[p] = (u16)b;
    }
    __syncthreads();

    // coalesced write-out: consecutive i in a bucket -> consecutive global slots
    for (int i = tid; i < cnt; i += 256) {
        int b = bslot[i];
        ebuf[gbase[b] + (i - lbase[b])] = sorted[i];
    }
}

// ---------- per-bucket finisher: hist + scan + row_ptr/dinv + col fill ----------
__global__ __launch_bounds__(1024) void bucket_finish_kernel(const int2* __restrict__ ebuf,
                                                             const int* __restrict__ bbase,
                                                             const int* __restrict__ btot,
                                                             int* __restrict__ col,
                                                             int* __restrict__ row_ptr,
                                                             float* __restrict__ dinv,
                                                             int N, int nbuck, long long E) {
    __shared__ int hist[NPB];
    __shared__ int scn[NPB];
    const int tid = threadIdx.x;
    const int b = blockIdx.x;
    const int e0 = bbase[b];
    const int tot = btot[b];
    const int base = b << NPB_SHIFT;

    if (tid < NPB) hist[tid] = 0;
    __syncthreads();
    for (int e = e0 + tid; e < e0 + tot; e += 1024)
        atomicAdd(&hist[ebuf[e].y - base], 1);
    __syncthreads();

    if (tid < NPB) scn[tid] = hist[tid];
    __syncthreads();
    for (int off = 1; off < NPB; off <<= 1) {
        int a = 0;
        if (tid < NPB && tid >= off) a = scn[tid - off];
        __syncthreads();
        if (tid < NPB && tid >= off) scn[tid] += a;
        __syncthreads();
    }

    int lim = N - base; if (lim > NPB) lim = NPB;
    if (tid < lim) {
        int h = hist[tid];
        int excl = scn[tid] - h;
        row_ptr[base + tid] = e0 + excl;
        dinv[base + tid] = rsqrtf((float)(h + 1));
    }
    if (b == nbuck - 1 && tid == 0) row_ptr[N] = (int)E;
    __syncthreads();

    if (tid < NPB) hist[tid] = e0 + (scn[tid] - hist[tid]);
    __syncthreads();
    for (int e = e0 + tid; e < e0 + tot; e += 1024) {
        int2 sd = ebuf[e];
        int p = atomicAdd(&hist[sd.y - base], 1);
        col[p] = sd.x;
    }
}

// ---------- prepack W (128x128 f32, row-major k x n) into MFMA B-frag order ----------
// One block per weight matrix.
__global__ __launch_bounds__(256) void prepack_w_kernel(const float* __restrict__ Wa,
                                                        const float* __restrict__ Wb,
                                                        const float* __restrict__ Wc,
                                                        u16* __restrict__ Wfa,
                                                        u16* __restrict__ Wfb,
                                                        u16* __restrict__ Wfc) {
    const float* W = (blockIdx.x == 0) ? Wa : (blockIdx.x == 1) ? Wb : Wc;
    u16* Wf = (blockIdx.x == 0) ? Wfa : (blockIdx.x == 1) ? Wfb : Wfc;
    for (int i = threadIdx.x; i < 16384; i += 256) {
        int j = i & 7;
        int lane = (i >> 3) & 63;
        int nb = (i >> 9) & 7;
        int kk = i >> 12;
        int k = kk * 32 + (lane >> 4) * 8 + j;
        int n = nb * 16 + (lane & 15);
        Wf[i] = f2h(W[k * 128 + n]);
    }
}

// ---------- MFMA GEMM: Y[M,128] = A[M,128] @ W(prepacked f16) ----------
// A is fp16 (Ah) or fp32 (Af, converted in-register). 4 waves/block,
// 32-row strip per wave. Epilogue: +bias, *scale(row); out fp16 or fp32.
__global__ __launch_bounds__(256) void mfma_gemm_kernel(const u16* __restrict__ Ah,
                                                        const float* __restrict__ Af,
                                                        const u16* __restrict__ Wf,
                                                        const float* __restrict__ bias,
                                                        const float* __restrict__ scale,
                                                        u16* __restrict__ Yh,
                                                        float* __restrict__ Yf, int M) {
    __shared__ u16 sB[4 * 8 * 64 * 8];  // 32 KB
    for (int i = threadIdx.x; i < 2048; i += 256)
        ((uint4*)sB)[i] = ((const uint4*)Wf)[i];
    __syncthreads();

    const int wid = threadIdx.x >> 6;
    const int lane = threadIdx.x & 63;
    const int lrow = lane & 15;
    const int lkb = lane >> 4;

    const int nstrip = (M + 31) / 32;
    for (int strip = blockIdx.x * 4 + wid; strip < nstrip; strip += gridDim.x * 4) {
        const int row0 = strip * 32;
        f16x8 a[2][4];
#pragma unroll
        for (int t = 0; t < 2; ++t)
#pragma unroll
            for (int kk = 0; kk < 4; ++kk) {
                if (Af) {
                    const float4* p = (const float4*)&Af[(size_t)(row0 + t * 16 + lrow) * FEAT +
                                                         kk * 32 + lkb * 8];
                    float4 u0 = p[0], u1 = p[1];
                    f16x8 av;
                    av[0] = (f16)u0.x; av[1] = (f16)u0.y; av[2] = (f16)u0.z; av[3] = (f16)u0.w;
                    av[4] = (f16)u1.x; av[5] = (f16)u1.y; av[6] = (f16)u1.z; av[7] = (f16)u1.w;
                    a[t][kk] = av;
                } else {
                    a[t][kk] = *(const f16x8*)&Ah[(size_t)(row0 + t * 16 + lrow) * FEAT +
                                                  kk * 32 + lkb * 8];
                }
            }
        f32x4 acc[2][8];
#pragma unroll
        for (int t = 0; t < 2; ++t)
#pragma unroll
            for (int nb = 0; nb < 8; ++nb) {
                acc[t][nb][0] = 0.f; acc[t][nb][1] = 0.f;
                acc[t][nb][2] = 0.f; acc[t][nb][3] = 0.f;
            }
#pragma unroll
        for (int kk = 0; kk < 4; ++kk)
#pragma unroll
            for (int nb = 0; nb < 8; ++nb) {
                f16x8 b = *(const f16x8*)&sB[((kk * 8 + nb) * 64 + lane) * 8];
                acc[0][nb] = __builtin_amdgcn_mfma_f32_16x16x32_f16(a[0][kk], b, acc[0][nb], 0, 0, 0);
                acc[1][nb] = __builtin_amdgcn_mfma_f32_16x16x32_f16(a[1][kk], b, acc[1][nb], 0, 0, 0);
            }
        // epilogue: C mapping col = lane&15, row = (lane>>4)*4 + r
#pragma unroll
        for (int t = 0; t < 2; ++t) {
#pragma unroll
            for (int nb = 0; nb < 8; ++nb) {
#pragma unroll
                for (int r = 0; r < 4; ++r) {
                    int row = row0 + t * 16 + (lane >> 4) * 4 + r;
                    int c = nb * 16 + (lane & 15);
                    float v = acc[t][nb][r];
                    if (bias) v += bias[c];
                    if (scale) v *= scale[row];
                    if (Yh) Yh[(size_t)row * FEAT + c] = f2h(v);
                    else    Yf[(size_t)row * FEAT + c] = v;
                }
            }
        }
    }
}

// ---------- gather: OUT[n] = relu(dinv[n]*(P'[n] + sum P'[col[e]]) + bias), fp16 out ----------
__global__ __launch_bounds__(256) void gather_kernel(const int* __restrict__ row_ptr,
                                                     const int* __restrict__ col,
                                                     const float* __restrict__ dinv,
                                                     const u16* __restrict__ Pb,
                                                     const float* __restrict__ bias,
                                                     u16* __restrict__ OUT,
                                                     int N, int doRelu) {
    const int lane = threadIdx.x & 15;
    const int grp = threadIdx.x >> 4;  // 0..15
    const int n = blockIdx.x * 16 + grp;
    if (n >= N) return;

    const float di = dinv[n];
    const int f8 = lane * 8;

    float a0, a1, a2, a3, a4, a5, a6, a7;
    {
        uint4 sv = *(const uint4*)&Pb[(size_t)n * FEAT + f8];
        float2 f0 = __half22float2(*(__half2*)&sv.x);
        float2 f1 = __half22float2(*(__half2*)&sv.y);
        float2 f2 = __half22float2(*(__half2*)&sv.z);
        float2 f3 = __half22float2(*(__half2*)&sv.w);
        a0 = f0.x; a1 = f0.y; a2 = f1.x; a3 = f1.y;
        a4 = f2.x; a5 = f2.y; a6 = f3.x; a7 = f3.y;
    }

#define ACC8(v) { \
        float2 f0 = __half22float2(*(__half2*)&(v).x); \
        float2 f1 = __half22float2(*(__half2*)&(v).y); \
        float2 f2 = __half22float2(*(__half2*)&(v).z); \
        float2 f3 = __half22float2(*(__half2*)&(v).w); \
        a0 += f0.x; a1 += f0.y; a2 += f1.x; a3 += f1.y; \
        a4 += f2.x; a5 += f2.y; a6 += f3.x; a7 += f3.y; }

    const int start = row_ptr[n];
    const int end = row_ptr[n + 1];

    for (int e0 = start; e0 < end; e0 += 16) {
        int mye = e0 + lane;
        int s = (mye < end) ? col[mye] : -1;
        int jmax = end - e0; if (jmax > 16) jmax = 16;
        int j = 0;
        for (; j + 3 < jmax; j += 4) {
            int s0 = __shfl(s, j, 16),     s1 = __shfl(s, j + 1, 16);
            int s2 = __shfl(s, j + 2, 16), s3 = __shfl(s, j + 3, 16);
            uint4 v0 = *(const uint4*)&Pb[(size_t)s0 * FEAT + f8];
            uint4 v1 = *(const uint4*)&Pb[(size_t)s1 * FEAT + f8];
            uint4 v2 = *(const uint4*)&Pb[(size_t)s2 * FEAT + f8];
            uint4 v3 = *(const uint4*)&Pb[(size_t)s3 * FEAT + f8];
            ACC8(v0); ACC8(v1); ACC8(v2); ACC8(v3);
        }
        for (; j < jmax; ++j) {
            int s0 = __shfl(s, j, 16);
            uint4 v0 = *(const uint4*)&Pb[(size_t)s0 * FEAT + f8];
            ACC8(v0);
        }
    }
#undef ACC8

    const float4 b0 = *(const float4*)&bias[f8];
    const float4 b1 = *(const float4*)&bias[f8 + 4];
    float r0 = a0 * di + b0.x, r1 = a1 * di + b0.y;
    float r2 = a2 * di + b0.z, r3 = a3 * di + b0.w;
    float r4 = a4 * di + b1.x, r5 = a5 * di + b1.y;
    float r6 = a6 * di + b1.z, r7 = a7 * di + b1.w;
    if (doRelu) {
        r0 = fmaxf(r0, 0.f); r1 = fmaxf(r1, 0.f); r2 = fmaxf(r2, 0.f); r3 = fmaxf(r3, 0.f);
        r4 = fmaxf(r4, 0.f); r5 = fmaxf(r5, 0.f); r6 = fmaxf(r6, 0.f); r7 = fmaxf(r7, 0.f);
    }
    ushort4 o0, o1;
    o0.x = f2h(r0); o0.y = f2h(r1); o0.z = f2h(r2); o0.w = f2h(r3);
    o1.x = f2h(r4); o1.y = f2h(r5); o1.z = f2h(r6); o1.w = f2h(r7);
    *(ushort4*)&OUT[(size_t)n * FEAT + f8] = o0;
    *(ushort4*)&OUT[(size_t)n * FEAT + f8 + 4] = o1;
}

extern "C" void kernel_launch(void* const* d_in, const int* in_sizes, int n_in,
                              void* d_out, int out_size, void* d_ws, size_t ws_size,
                              hipStream_t stream) {
    const float* x  = (const float*)d_in[0];
    const int*   ei = (const int*)d_in[1];
    const float* W1 = (const float*)d_in[2];
    const float* b1 = (const float*)d_in[3];
    const float* W2 = (const float*)d_in[4];
    const float* b2 = (const float*)d_in[5];
    const float* Wl = (const float*)d_in[6];
    const float* bl = (const float*)d_in[7];
    float* out = (float*)d_out;

    const int N = in_sizes[0] / FEAT;      // 100000
    const long long E = in_sizes[1] / 2;   // 3200000
    const int* src = ei;
    const int* dst = ei + E;

    const int nbuck = (N + NPB - 1) >> NPB_SHIFT;    // 196
    const int nchunks = (int)((E + EPB - 1) / EPB);  // 782
    const int nblk = ((nchunks + 7) / 8) * 8;        // 784

    // workspace layout (~66 MB)
    u16*   H       = (u16*)d_ws;                       // N*128 fp16 (aliases ebuf)
    u16*   Pb      = H + (long long)N * FEAT;          // N*128 fp16
    float* dinv    = (float*)(Pb + (long long)N * FEAT);
    int*   row_ptr = (int*)(dinv + N);                 // N+1
    int*   btot    = row_ptr + N + 1;                  // 256
    int*   bbase   = btot + 256;                       // 256
    int*   cmat    = bbase + 256;                      // nbuck*nblk
    u16*   Wf1     = (u16*)(cmat + (long long)nbuck * nblk);  // 16384
    u16*   Wf2     = Wf1 + 16384;
    u16*   Wfl     = Wf2 + 16384;
    int*   col     = (int*)(Wfl + 16384);              // E
    int2*  ebuf    = (int2*)H;                         // E int2 (25.6MB)

    // ---- bucket radix: sort edges by dst bucket ----
    radix_count_kernel<<<nblk, 256, 0, stream>>>(dst, cmat, E, nbuck, nblk);
    radix_btot_kernel<<<nbuck, 256, 0, stream>>>(cmat, btot, nblk);
    radix_bscan_kernel<<<1, 256, 0, stream>>>(btot, bbase, nbuck);
    radix_colscan_kernel<<<nbuck, 256, 0, stream>>>(cmat, bbase, nblk);
    radix_scatter_kernel<<<nblk, 256, 0, stream>>>(src, dst, cmat, ebuf, E, nbuck, nblk);

    // ---- per-bucket finisher: row_ptr, dinv, col (consumes ebuf) ----
    bucket_finish_kernel<<<nbuck, 1024, 0, stream>>>(ebuf, bbase, btot, col, row_ptr,
                                                     dinv, N, nbuck, E);

    // ---- weight prepack (one launch, 3 blocks) ----
    prepack_w_kernel<<<3, 256, 0, stream>>>(W1, W2, Wl, Wf1, Wf2, Wfl);

    const int gemmGrid = ((N + 31) / 32 + 3) / 4;
    const int gatherBlocks = (N + 15) / 16;

    // ---- layer 1: P' = dinv * (x @ W1), fp16 (fused fp32->fp16 A-load) ----
    mfma_gemm_kernel<<<gemmGrid, 256, 0, stream>>>(nullptr, x, Wf1, nullptr, dinv,
                                                   Pb, nullptr, N);
    gather_kernel<<<gatherBlocks, 256, 0, stream>>>(row_ptr, col, dinv, Pb, b1, H, N, 1);

    // ---- layer 2 ----
    mfma_gemm_kernel<<<gemmGrid, 256, 0, stream>>>(H, nullptr, Wf2, nullptr, dinv,
                                                   Pb, nullptr, N);
    gather_kernel<<<gatherBlocks, 256, 0, stream>>>(row_ptr, col, dinv, Pb, b2, H, N, 1);

    // ---- output head: out = h2 @ Wl + bl (fp32) ----
    mfma_gemm_kernel<<<gemmGrid, 256, 0, stream>>>(H, nullptr, Wfl, bl, nullptr,
                                                   nullptr, out, N);
}

// Round 9
// 356.458 us; speedup vs baseline: 31.2843x; 1.1612x over previous
//
#include <hip/hip_runtime.h>
#include <hip/hip_bf16.h>
#include <hip/hip_fp16.h>

// GCN: h1 = relu(gcn(x, W1, b1)); h2 = relu(gcn(h1, W2, b2)); out = h2@Wl + bl
// gcn(x,W,b) = D^-1/2 (A+I) D^-1/2 (xW) + b, deg = in-degree(dst)+1
// Pipeline: CSR build (bucket radix by dst>>9, packed u32 ebuf, LDS finisher)
//   -> mfma_gemm1: P1' = dinv * (x @ W1)            (fp32 x in-reg converted)
//   -> gather+GEMM fused: h1 = relu(dinv*agg(P1')+b1); P2' = dinv*(h1@W2)
//   -> gather+GEMM fused: h2 = relu(dinv*agg(P2')+b2); out = h2@Wl + bl
// Aggregation accumulates fp32; P' stored fp16; tile staged in swizzled LDS.

#define FEAT 128
#define EPB 4096       // edges per radix chunk
#define NPB_SHIFT 9    // 512 nodes per bucket
#define NPB (1 << NPB_SHIFT)

typedef unsigned short u16;
typedef unsigned int u32;
typedef _Float16 f16;
typedef __attribute__((ext_vector_type(8))) _Float16 f16x8;
typedef __attribute__((ext_vector_type(4))) float f32x4;

static __device__ __forceinline__ u16 f2h(float f) {
    f16 h = (f16)f;
    return *reinterpret_cast<u16*>(&h);
}

// ---------- bucket radix: count per (bucket, chunk) ----------
__global__ __launch_bounds__(256) void radix_count_kernel(const int* __restrict__ dst,
                                                          int* __restrict__ cmat,
                                                          long long E, int nbuck, int nblk) {
    __shared__ int h[256];
    int blk = blockIdx.x;
    for (int i = threadIdx.x; i < nbuck; i += 256) h[i] = 0;
    __syncthreads();
    long long e0 = (long long)blk * EPB;
    long long eend = e0 + EPB; if (eend > E) eend = E;
    for (long long e = e0 + threadIdx.x; e < eend; e += 256)
        atomicAdd(&h[dst[e] >> NPB_SHIFT], 1);
    __syncthreads();
    for (int i = threadIdx.x; i < nbuck; i += 256)
        cmat[(long long)i * nblk + blk] = h[i];
}

__global__ __launch_bounds__(256) void radix_btot_kernel(const int* __restrict__ cmat,
                                                         int* __restrict__ btot, int nblk) {
    __shared__ int tmp[256];
    long long row = (long long)blockIdx.x * nblk;
    int s = 0;
    for (int i = threadIdx.x; i < nblk; i += 256) s += cmat[row + i];
    tmp[threadIdx.x] = s;
    __syncthreads();
    for (int off = 128; off > 0; off >>= 1) {
        if (threadIdx.x < off) tmp[threadIdx.x] += tmp[threadIdx.x + off];
        __syncthreads();
    }
    if (threadIdx.x == 0) btot[blockIdx.x] = tmp[0];
}

__global__ __launch_bounds__(256) void radix_bscan_kernel(const int* __restrict__ btot,
                                                          int* __restrict__ bbase, int nbuck) {
    __shared__ int tmp[256];
    int t = threadIdx.x;
    int v = (t < nbuck) ? btot[t] : 0;
    tmp[t] = v;
    __syncthreads();
    for (int off = 1; off < 256; off <<= 1) {
        int a = (t >= off) ? tmp[t - off] : 0;
        __syncthreads();
        tmp[t] += a;
        __syncthreads();
    }
    if (t < nbuck) bbase[t] = tmp[t] - v;
}

__global__ __launch_bounds__(256) void radix_colscan_kernel(int* __restrict__ cmat,
                                                            const int* __restrict__ bbase,
                                                            int nblk) {
    __shared__ int tmp[256];
    __shared__ int carry;
    long long row = (long long)blockIdx.x * nblk;
    if (threadIdx.x == 0) carry = bbase[blockIdx.x];
    __syncthreads();
    for (int c0 = 0; c0 < nblk; c0 += 256) {
        int i = c0 + threadIdx.x;
        int v = (i < nblk) ? cmat[row + i] : 0;
        tmp[threadIdx.x] = v;
        __syncthreads();
        for (int off = 1; off < 256; off <<= 1) {
            int a = (threadIdx.x >= off) ? tmp[threadIdx.x - off] : 0;
            __syncthreads();
            tmp[threadIdx.x] += a;
            __syncthreads();
        }
        if (i < nblk) cmat[row + i] = tmp[threadIdx.x] - v + carry;
        __syncthreads();
        if (threadIdx.x == 0) carry += tmp[255];
        __syncthreads();
    }
}

// ---------- scatter: block-local LDS counting sort -> coalesced packed writes ----------
// packed edge: (src << NPB_SHIFT) | (dst & (NPB-1)); bucket id kept separately.
__global__ __launch_bounds__(256) void radix_scatter_kernel(const int* __restrict__ src,
                                                            const int* __restrict__ dst,
                                                            const int* __restrict__ cmat,
                                                            u32* __restrict__ ebuf,
                                                            long long E, int nbuck, int nblk) {
    __shared__ int gbase[256];
    __shared__ int lbase[256];
    __shared__ int lofs[256];
    __shared__ u16 bslot[EPB];
    __shared__ u32 sorted[EPB];
    const int blk = blockIdx.x;
    const int tid = threadIdx.x;
    long long e0 = (long long)blk * EPB;
    if (e0 >= E) return;
    const int cnt = (int)((E - e0 < EPB) ? (E - e0) : EPB);

    int v = 0;
    if (tid < nbuck) {
        int base = cmat[(long long)tid * nblk + blk];
        int nxt;
        if (blk + 1 < nblk) nxt = cmat[(long long)tid * nblk + blk + 1];
        else nxt = (tid + 1 < nbuck) ? cmat[(long long)(tid + 1) * nblk] : (int)E;
        gbase[tid] = base;
        v = nxt - base;
    }
    lbase[tid] = v;
    lofs[tid] = v;
    __syncthreads();
    for (int off = 1; off < 256; off <<= 1) {
        int a = (tid >= off) ? lbase[tid - off] : 0;
        __syncthreads();
        lbase[tid] += a;
        __syncthreads();
    }
    int excl = lbase[tid] - lofs[tid];
    __syncthreads();
    lbase[tid] = excl;
    lofs[tid] = excl;
    __syncthreads();

    for (int i = tid; i < cnt; i += 256) {
        int d = dst[e0 + i];
        int b = d >> NPB_SHIFT;
        int p = atomicAdd(&lofs[b], 1);
        sorted[p] = ((u32)src[e0 + i] << NPB_SHIFT) | (u32)(d & (NPB - 1));
        bslot[p] = (u16)b;
    }
    __syncthreads();

    for (int i = tid; i < cnt; i += 256) {
        int b = bslot[i];
        ebuf[gbase[b] + (i - lbase[b])] = sorted[i];
    }
}

// ---------- per-bucket finisher: hist + scan + row_ptr/dinv + col fill ----------
__global__ __launch_bounds__(1024) void bucket_finish_kernel(const u32* __restrict__ ebuf,
                                                             const int* __restrict__ bbase,
                                                             const int* __restrict__ btot,
                                                             int* __restrict__ col,
                                                             int* __restrict__ row_ptr,
                                                             float* __restrict__ dinv,
                                                             int N, int nbuck, long long E) {
    __shared__ int hist[NPB];
    __shared__ int scn[NPB];
    const int tid = threadIdx.x;
    const int b = blockIdx.x;
    const int e0 = bbase[b];
    const int tot = btot[b];
    const int base = b << NPB_SHIFT;

    if (tid < NPB) hist[tid] = 0;
    __syncthreads();
    for (int e = e0 + tid; e < e0 + tot; e += 1024)
        atomicAdd(&hist[ebuf[e] & (NPB - 1)], 1);
    __syncthreads();

    if (tid < NPB) scn[tid] = hist[tid];
    __syncthreads();
    for (int off = 1; off < NPB; off <<= 1) {
        int a = 0;
        if (tid < NPB && tid >= off) a = scn[tid - off];
        __syncthreads();
        if (tid < NPB && tid >= off) scn[tid] += a;
        __syncthreads();
    }

    int lim = N - base; if (lim > NPB) lim = NPB;
    if (tid < lim) {
        int h = hist[tid];
        int excl = scn[tid] - h;
        row_ptr[base + tid] = e0 + excl;
        dinv[base + tid] = rsqrtf((float)(h + 1));
    }
    if (b == nbuck - 1 && tid == 0) row_ptr[N] = (int)E;
    __syncthreads();

    if (tid < NPB) hist[tid] = e0 + (scn[tid] - hist[tid]);
    __syncthreads();
    for (int e = e0 + tid; e < e0 + tot; e += 1024) {
        u32 sd = ebuf[e];
        int p = atomicAdd(&hist[sd & (NPB - 1)], 1);
        col[p] = (int)(sd >> NPB_SHIFT);
    }
}

// ---------- prepack W (128x128 f32, row-major k x n) into MFMA B-frag order ----------
__global__ __launch_bounds__(256) void prepack_w_kernel(const float* __restrict__ Wa,
                                                        const float* __restrict__ Wb,
                                                        const float* __restrict__ Wc,
                                                        u16* __restrict__ Wfa,
                                                        u16* __restrict__ Wfb,
                                                        u16* __restrict__ Wfc) {
    const float* W = (blockIdx.x == 0) ? Wa : (blockIdx.x == 1) ? Wb : Wc;
    u16* Wf = (blockIdx.x == 0) ? Wfa : (blockIdx.x == 1) ? Wfb : Wfc;
    for (int i = threadIdx.x; i < 16384; i += 256) {
        int j = i & 7;
        int lane = (i >> 3) & 63;
        int nb = (i >> 9) & 7;
        int kk = i >> 12;
        int k = kk * 32 + (lane >> 4) * 8 + j;
        int n = nb * 16 + (lane & 15);
        Wf[i] = f2h(W[k * 128 + n]);
    }
}

// ---------- layer-1 GEMM: P1' = dinv * (x @ W1), fp32 x converted in-register ----------
__global__ __launch_bounds__(256) void mfma_gemm1_kernel(const float* __restrict__ Af,
                                                         const u16* __restrict__ Wf,
                                                         const float* __restrict__ scale,
                                                         u16* __restrict__ Yh, int M) {
    __shared__ u16 sB[16384];  // 32 KB
    for (int i = threadIdx.x; i < 2048; i += 256)
        ((uint4*)sB)[i] = ((const uint4*)Wf)[i];
    __syncthreads();

    const int wid = threadIdx.x >> 6;
    const int lane = threadIdx.x & 63;
    const int lrow = lane & 15;
    const int lkb = lane >> 4;

    const int nstrip = (M + 31) / 32;
    for (int strip = blockIdx.x * 4 + wid; strip < nstrip; strip += gridDim.x * 4) {
        const int row0 = strip * 32;
        f16x8 a[2][4];
#pragma unroll
        for (int t = 0; t < 2; ++t)
#pragma unroll
            for (int kk = 0; kk < 4; ++kk) {
                const float4* p = (const float4*)&Af[(size_t)(row0 + t * 16 + lrow) * FEAT +
                                                     kk * 32 + lkb * 8];
                float4 u0 = p[0], u1 = p[1];
                f16x8 av;
                av[0] = (f16)u0.x; av[1] = (f16)u0.y; av[2] = (f16)u0.z; av[3] = (f16)u0.w;
                av[4] = (f16)u1.x; av[5] = (f16)u1.y; av[6] = (f16)u1.z; av[7] = (f16)u1.w;
                a[t][kk] = av;
            }
        f32x4 acc[2][8];
#pragma unroll
        for (int t = 0; t < 2; ++t)
#pragma unroll
            for (int nb = 0; nb < 8; ++nb) {
                acc[t][nb][0] = 0.f; acc[t][nb][1] = 0.f;
                acc[t][nb][2] = 0.f; acc[t][nb][3] = 0.f;
            }
#pragma unroll
        for (int kk = 0; kk < 4; ++kk)
#pragma unroll
            for (int nb = 0; nb < 8; ++nb) {
                f16x8 b = *(const f16x8*)&sB[((kk * 8 + nb) * 64 + lane) * 8];
                acc[0][nb] = __builtin_amdgcn_mfma_f32_16x16x32_f16(a[0][kk], b, acc[0][nb], 0, 0, 0);
                acc[1][nb] = __builtin_amdgcn_mfma_f32_16x16x32_f16(a[1][kk], b, acc[1][nb], 0, 0, 0);
            }
#pragma unroll
        for (int t = 0; t < 2; ++t)
#pragma unroll
            for (int nb = 0; nb < 8; ++nb)
#pragma unroll
                for (int r = 0; r < 4; ++r) {
                    int row = row0 + t * 16 + (lane >> 4) * 4 + r;
                    int c = nb * 16 + (lane & 15);
                    Yh[(size_t)row * FEAT + c] = f2h(acc[t][nb][r] * scale[row]);
                }
    }
}

// ---------- fused gather + next-layer GEMM ----------
// Per block: 16 dst rows. Phase 1: agg fp32 from Pin (fp16 rows, pre-scaled by
// dinv[src]) -> h = relu(dinv[n]*acc + aggBias) -> fp16 tile in swizzled LDS.
// Phase 2: tile @ Wf via MFMA -> epilogue (dinv-scale for P' fp16, or +headBias
// fp32 for the final output).
__global__ __launch_bounds__(256) void gather_gemm_kernel(const int* __restrict__ row_ptr,
                                                          const int* __restrict__ col,
                                                          const float* __restrict__ dinv,
                                                          const u16* __restrict__ Pin,
                                                          const float* __restrict__ aggBias,
                                                          const u16* __restrict__ Wf,
                                                          const float* __restrict__ headBias,
                                                          u16* __restrict__ Yh,
                                                          float* __restrict__ Yf, int N) {
    __shared__ u16 sB[16384];     // 32 KB prepacked W
    __shared__ u16 tile[16 * 128];  // 4 KB, XOR-swizzled rows

    // stage W (overlaps with gather phase; barrier below orders LDS)
    for (int i = threadIdx.x; i < 2048; i += 256)
        ((uint4*)sB)[i] = ((const uint4*)Wf)[i];

    const int lane16 = threadIdx.x & 15;
    const int grp = threadIdx.x >> 4;  // 0..15
    const int row0 = blockIdx.x * 16;
    const int n = row0 + grp;
    const int f8 = lane16 * 8;

    float a0 = 0.f, a1 = 0.f, a2 = 0.f, a3 = 0.f;
    float a4 = 0.f, a5 = 0.f, a6 = 0.f, a7 = 0.f;

    if (n < N) {
        const float di = dinv[n];
        {
            uint4 sv = *(const uint4*)&Pin[(size_t)n * FEAT + f8];
            float2 f0 = __half22float2(*(__half2*)&sv.x);
            float2 f1 = __half22float2(*(__half2*)&sv.y);
            float2 f2 = __half22float2(*(__half2*)&sv.z);
            float2 f3 = __half22float2(*(__half2*)&sv.w);
            a0 = f0.x; a1 = f0.y; a2 = f1.x; a3 = f1.y;
            a4 = f2.x; a5 = f2.y; a6 = f3.x; a7 = f3.y;
        }
#define ACC8(v) { \
        float2 f0 = __half22float2(*(__half2*)&(v).x); \
        float2 f1 = __half22float2(*(__half2*)&(v).y); \
        float2 f2 = __half22float2(*(__half2*)&(v).z); \
        float2 f3 = __half22float2(*(__half2*)&(v).w); \
        a0 += f0.x; a1 += f0.y; a2 += f1.x; a3 += f1.y; \
        a4 += f2.x; a5 += f2.y; a6 += f3.x; a7 += f3.y; }
        const int start = row_ptr[n];
        const int end = row_ptr[n + 1];
        for (int e0 = start; e0 < end; e0 += 16) {
            int mye = e0 + lane16;
            int s = (mye < end) ? col[mye] : -1;
            int jmax = end - e0; if (jmax > 16) jmax = 16;
            int j = 0;
            for (; j + 3 < jmax; j += 4) {
                int s0 = __shfl(s, j, 16),     s1 = __shfl(s, j + 1, 16);
                int s2 = __shfl(s, j + 2, 16), s3 = __shfl(s, j + 3, 16);
                uint4 v0 = *(const uint4*)&Pin[(size_t)s0 * FEAT + f8];
                uint4 v1 = *(const uint4*)&Pin[(size_t)s1 * FEAT + f8];
                uint4 v2 = *(const uint4*)&Pin[(size_t)s2 * FEAT + f8];
                uint4 v3 = *(const uint4*)&Pin[(size_t)s3 * FEAT + f8];
                ACC8(v0); ACC8(v1); ACC8(v2); ACC8(v3);
            }
            for (; j < jmax; ++j) {
                int s0 = __shfl(s, j, 16);
                uint4 v0 = *(const uint4*)&Pin[(size_t)s0 * FEAT + f8];
                ACC8(v0);
            }
        }
#undef ACC8
        const float4 b0 = *(const float4*)&aggBias[f8];
        const float4 b1 = *(const float4*)&aggBias[f8 + 4];
        a0 = fmaxf(a0 * di + b0.x, 0.f); a1 = fmaxf(a1 * di + b0.y, 0.f);
        a2 = fmaxf(a2 * di + b0.z, 0.f); a3 = fmaxf(a3 * di + b0.w, 0.f);
        a4 = fmaxf(a4 * di + b1.x, 0.f); a5 = fmaxf(a5 * di + b1.y, 0.f);
        a6 = fmaxf(a6 * di + b1.z, 0.f); a7 = fmaxf(a7 * di + b1.w, 0.f);
    }

    // write h row into swizzled LDS tile (zeros for n >= N)
    {
        f16x8 hv;
        hv[0] = (f16)a0; hv[1] = (f16)a1; hv[2] = (f16)a2; hv[3] = (f16)a3;
        hv[4] = (f16)a4; hv[5] = (f16)a5; hv[6] = (f16)a6; hv[7] = (f16)a7;
        *(f16x8*)&tile[grp * 128 + ((lane16 * 8) ^ ((grp & 7) << 3))] = hv;
    }
    __syncthreads();

    // Phase 2: 4 waves x 2 n-blocks; A-frags from swizzled tile
    const int lane = threadIdx.x & 63;
    const int wid = threadIdx.x >> 6;
    const int trow = lane & 15;
    f16x8 af[4];
#pragma unroll
    for (int kk = 0; kk < 4; ++kk)
        af[kk] = *(const f16x8*)&tile[trow * 128 +
                                      ((kk * 32 + (lane >> 4) * 8) ^ ((trow & 7) << 3))];
#pragma unroll
    for (int nb2 = 0; nb2 < 2; ++nb2) {
        const int nb = wid * 2 + nb2;
        f32x4 acc;
        acc[0] = 0.f; acc[1] = 0.f; acc[2] = 0.f; acc[3] = 0.f;
#pragma unroll
        for (int kk = 0; kk < 4; ++kk) {
            f16x8 b = *(const f16x8*)&sB[((kk * 8 + nb) * 64 + lane) * 8];
            acc = __builtin_amdgcn_mfma_f32_16x16x32_f16(af[kk], b, acc, 0, 0, 0);
        }
        const int c = nb * 16 + (lane & 15);
#pragma unroll
        for (int r = 0; r < 4; ++r) {
            int row = row0 + (lane >> 4) * 4 + r;
            if (row < N) {
                float v = acc[r];
                if (Yh) {
                    Yh[(size_t)row * FEAT + c] = f2h(v * dinv[row]);
                } else {
                    Yf[(size_t)row * FEAT + c] = v + headBias[c];
                }
            }
        }
    }
}

extern "C" void kernel_launch(void* const* d_in, const int* in_sizes, int n_in,
                              void* d_out, int out_size, void* d_ws, size_t ws_size,
                              hipStream_t stream) {
    const float* x  = (const float*)d_in[0];
    const int*   ei = (const int*)d_in[1];
    const float* W1 = (const float*)d_in[2];
    const float* b1 = (const float*)d_in[3];
    const float* W2 = (const float*)d_in[4];
    const float* b2 = (const float*)d_in[5];
    const float* Wl = (const float*)d_in[6];
    const float* bl = (const float*)d_in[7];
    float* out = (float*)d_out;

    const int N = in_sizes[0] / FEAT;      // 100000
    const long long E = in_sizes[1] / 2;   // 3200000
    const int* src = ei;
    const int* dst = ei + E;

    const int nbuck = (N + NPB - 1) >> NPB_SHIFT;    // 196
    const int nchunks = (int)((E + EPB - 1) / EPB);  // 782
    const int nblk = ((nchunks + 7) / 8) * 8;        // 784

    // workspace layout (~68 MB)
    u16*   PbA     = (u16*)d_ws;                       // N*128 fp16 (aliases ebuf)
    u16*   PbB     = PbA + (long long)N * FEAT;        // N*128 fp16
    float* dinv    = (float*)(PbB + (long long)N * FEAT);
    int*   row_ptr = (int*)(dinv + N);                 // N+1
    int*   btot    = row_ptr + N + 1;                  // 256
    int*   bbase   = btot + 256;                       // 256
    int*   cmat    = bbase + 256;                      // nbuck*nblk
    u16*   Wf1     = (u16*)(cmat + (long long)nbuck * nblk);  // 16384
    u16*   Wf2     = Wf1 + 16384;
    u16*   Wfl     = Wf2 + 16384;
    int*   col     = (int*)(Wfl + 16384);              // E
    u32*   ebuf    = (u32*)PbA;                        // E u32 (12.8MB, in PbA)

    // ---- bucket radix: sort edges by dst bucket (packed u32) ----
    radix_count_kernel<<<nblk, 256, 0, stream>>>(dst, cmat, E, nbuck, nblk);
    radix_btot_kernel<<<nbuck, 256, 0, stream>>>(cmat, btot, nblk);
    radix_bscan_kernel<<<1, 256, 0, stream>>>(btot, bbase, nbuck);
    radix_colscan_kernel<<<nbuck, 256, 0, stream>>>(cmat, bbase, nblk);
    radix_scatter_kernel<<<nblk, 256, 0, stream>>>(src, dst, cmat, ebuf, E, nbuck, nblk);

    // ---- per-bucket finisher: row_ptr, dinv, col (consumes ebuf) ----
    bucket_finish_kernel<<<nbuck, 1024, 0, stream>>>(ebuf, bbase, btot, col, row_ptr,
                                                     dinv, N, nbuck, E);

    // ---- weight prepack ----
    prepack_w_kernel<<<3, 256, 0, stream>>>(W1, W2, Wl, Wf1, Wf2, Wfl);

    const int gemmGrid = ((N + 31) / 32 + 3) / 4;
    const int fusedGrid = (N + 15) / 16;

    // ---- layer 1 projection: P1' = dinv * (x @ W1) (writes PbA; ebuf consumed) ----
    mfma_gemm1_kernel<<<gemmGrid, 256, 0, stream>>>(x, Wf1, dinv, PbA, N);

    // ---- h1 agg + layer-2 projection: P2' = dinv * (relu(agg)@W2) ----
    gather_gemm_kernel<<<fusedGrid, 256, 0, stream>>>(row_ptr, col, dinv, PbA, b1,
                                                      Wf2, nullptr, PbB, nullptr, N);

    // ---- h2 agg + head: out = relu(agg) @ Wl + bl ----
    gather_gemm_kernel<<<fusedGrid, 256, 0, stream>>>(row_ptr, col, dinv, PbB, b2,
                                                      Wfl, bl, nullptr, out, N);
}

// Round 10
// 331.972 us; speedup vs baseline: 33.5918x; 1.0738x over previous
//
#include <hip/hip_runtime.h>
#include <hip/hip_bf16.h>
#include <hip/hip_fp16.h>

// GCN: h1 = relu(gcn(x, W1, b1)); h2 = relu(gcn(h1, W2, b2)); out = h2@Wl + bl
// gcn(x,W,b) = D^-1/2 (A+I) D^-1/2 (xW) + b, deg = in-degree(dst)+1
// Pipeline: CSR build (bucket radix by dst>>9, packed u32 ebuf, LDS finisher)
//   -> mfma_gemm1: P1' = dinv * (x @ W1)            (fp32 x in-reg converted)
//   -> gather+GEMM fused: h1 = relu(dinv*agg(P1')+b1); P2' = dinv*(h1@W2)
//   -> gather+GEMM fused: h2 = relu(dinv*agg(P2')+b2); out = h2@Wl + bl
// Fused kernel keeps LDS at 4KB (h-tile only); W fragments are loaded
// directly from global (L2-resident 32KB) to preserve occupancy for the
// latency-bound random gather. Aggregation fp32; P' fp16.

#define FEAT 128
#define EPB 4096       // edges per radix chunk
#define NPB_SHIFT 9    // 512 nodes per bucket
#define NPB (1 << NPB_SHIFT)

typedef unsigned short u16;
typedef unsigned int u32;
typedef _Float16 f16;
typedef __attribute__((ext_vector_type(8))) _Float16 f16x8;
typedef __attribute__((ext_vector_type(4))) float f32x4;

static __device__ __forceinline__ u16 f2h(float f) {
    f16 h = (f16)f;
    return *reinterpret_cast<u16*>(&h);
}

// ---------- bucket radix: count per (bucket, chunk) ----------
__global__ __launch_bounds__(256) void radix_count_kernel(const int* __restrict__ dst,
                                                          int* __restrict__ cmat,
                                                          long long E, int nbuck, int nblk) {
    __shared__ int h[256];
    int blk = blockIdx.x;
    for (int i = threadIdx.x; i < nbuck; i += 256) h[i] = 0;
    __syncthreads();
    long long e0 = (long long)blk * EPB;
    long long eend = e0 + EPB; if (eend > E) eend = E;
    for (long long e = e0 + threadIdx.x; e < eend; e += 256)
        atomicAdd(&h[dst[e] >> NPB_SHIFT], 1);
    __syncthreads();
    for (int i = threadIdx.x; i < nbuck; i += 256)
        cmat[(long long)i * nblk + blk] = h[i];
}

__global__ __launch_bounds__(256) void radix_btot_kernel(const int* __restrict__ cmat,
                                                         int* __restrict__ btot, int nblk) {
    __shared__ int tmp[256];
    long long row = (long long)blockIdx.x * nblk;
    int s = 0;
    for (int i = threadIdx.x; i < nblk; i += 256) s += cmat[row + i];
    tmp[threadIdx.x] = s;
    __syncthreads();
    for (int off = 128; off > 0; off >>= 1) {
        if (threadIdx.x < off) tmp[threadIdx.x] += tmp[threadIdx.x + off];
        __syncthreads();
    }
    if (threadIdx.x == 0) btot[blockIdx.x] = tmp[0];
}

__global__ __launch_bounds__(256) void radix_bscan_kernel(const int* __restrict__ btot,
                                                          int* __restrict__ bbase, int nbuck) {
    __shared__ int tmp[256];
    int t = threadIdx.x;
    int v = (t < nbuck) ? btot[t] : 0;
    tmp[t] = v;
    __syncthreads();
    for (int off = 1; off < 256; off <<= 1) {
        int a = (t >= off) ? tmp[t - off] : 0;
        __syncthreads();
        tmp[t] += a;
        __syncthreads();
    }
    if (t < nbuck) bbase[t] = tmp[t] - v;
}

__global__ __launch_bounds__(256) void radix_colscan_kernel(int* __restrict__ cmat,
                                                            const int* __restrict__ bbase,
                                                            int nblk) {
    __shared__ int tmp[256];
    __shared__ int carry;
    long long row = (long long)blockIdx.x * nblk;
    if (threadIdx.x == 0) carry = bbase[blockIdx.x];
    __syncthreads();
    for (int c0 = 0; c0 < nblk; c0 += 256) {
        int i = c0 + threadIdx.x;
        int v = (i < nblk) ? cmat[row + i] : 0;
        tmp[threadIdx.x] = v;
        __syncthreads();
        for (int off = 1; off < 256; off <<= 1) {
            int a = (threadIdx.x >= off) ? tmp[threadIdx.x - off] : 0;
            __syncthreads();
            tmp[threadIdx.x] += a;
            __syncthreads();
        }
        if (i < nblk) cmat[row + i] = tmp[threadIdx.x] - v + carry;
        __syncthreads();
        if (threadIdx.x == 0) carry += tmp[255];
        __syncthreads();
    }
}

// ---------- scatter: block-local LDS counting sort -> coalesced packed writes ----------
__global__ __launch_bounds__(256) void radix_scatter_kernel(const int* __restrict__ src,
                                                            const int* __restrict__ dst,
                                                            const int* __restrict__ cmat,
                                                            u32* __restrict__ ebuf,
                                                            long long E, int nbuck, int nblk) {
    __shared__ int gbase[256];
    __shared__ int lbase[256];
    __shared__ int lofs[256];
    __shared__ u16 bslot[EPB];
    __shared__ u32 sorted[EPB];
    const int blk = blockIdx.x;
    const int tid = threadIdx.x;
    long long e0 = (long long)blk * EPB;
    if (e0 >= E) return;
    const int cnt = (int)((E - e0 < EPB) ? (E - e0) : EPB);

    int v = 0;
    if (tid < nbuck) {
        int base = cmat[(long long)tid * nblk + blk];
        int nxt;
        if (blk + 1 < nblk) nxt = cmat[(long long)tid * nblk + blk + 1];
        else nxt = (tid + 1 < nbuck) ? cmat[(long long)(tid + 1) * nblk] : (int)E;
        gbase[tid] = base;
        v = nxt - base;
    }
    lbase[tid] = v;
    lofs[tid] = v;
    __syncthreads();
    for (int off = 1; off < 256; off <<= 1) {
        int a = (tid >= off) ? lbase[tid - off] : 0;
        __syncthreads();
        lbase[tid] += a;
        __syncthreads();
    }
    int excl = lbase[tid] - lofs[tid];
    __syncthreads();
    lbase[tid] = excl;
    lofs[tid] = excl;
    __syncthreads();

    for (int i = tid; i < cnt; i += 256) {
        int d = dst[e0 + i];
        int b = d >> NPB_SHIFT;
        int p = atomicAdd(&lofs[b], 1);
        sorted[p] = ((u32)src[e0 + i] << NPB_SHIFT) | (u32)(d & (NPB - 1));
        bslot[p] = (u16)b;
    }
    __syncthreads();

    for (int i = tid; i < cnt; i += 256) {
        int b = bslot[i];
        ebuf[gbase[b] + (i - lbase[b])] = sorted[i];
    }
}

// ---------- per-bucket finisher: hist + scan + row_ptr/dinv + col fill ----------
__global__ __launch_bounds__(1024) void bucket_finish_kernel(const u32* __restrict__ ebuf,
                                                             const int* __restrict__ bbase,
                                                             const int* __restrict__ btot,
                                                             int* __restrict__ col,
                                                             int* __restrict__ row_ptr,
                                                             float* __restrict__ dinv,
                                                             int N, int nbuck, long long E) {
    __shared__ int hist[NPB];
    __shared__ int scn[NPB];
    const int tid = threadIdx.x;
    const int b = blockIdx.x;
    const int e0 = bbase[b];
    const int tot = btot[b];
    const int base = b << NPB_SHIFT;

    if (tid < NPB) hist[tid] = 0;
    __syncthreads();
    for (int e = e0 + tid; e < e0 + tot; e += 1024)
        atomicAdd(&hist[ebuf[e] & (NPB - 1)], 1);
    __syncthreads();

    if (tid < NPB) scn[tid] = hist[tid];
    __syncthreads();
    for (int off = 1; off < NPB; off <<= 1) {
        int a = 0;
        if (tid < NPB && tid >= off) a = scn[tid - off];
        __syncthreads();
        if (tid < NPB && tid >= off) scn[tid] += a;
        __syncthreads();
    }

    int lim = N - base; if (lim > NPB) lim = NPB;
    if (tid < lim) {
        int h = hist[tid];
        int excl = scn[tid] - h;
        row_ptr[base + tid] = e0 + excl;
        dinv[base + tid] = rsqrtf((float)(h + 1));
    }
    if (b == nbuck - 1 && tid == 0) row_ptr[N] = (int)E;
    __syncthreads();

    if (tid < NPB) hist[tid] = e0 + (scn[tid] - hist[tid]);
    __syncthreads();
    for (int e = e0 + tid; e < e0 + tot; e += 1024) {
        u32 sd = ebuf[e];
        int p = atomicAdd(&hist[sd & (NPB - 1)], 1);
        col[p] = (int)(sd >> NPB_SHIFT);
    }
}

// ---------- prepack W (128x128 f32, row-major k x n) into MFMA B-frag order ----------
__global__ __launch_bounds__(256) void prepack_w_kernel(const float* __restrict__ Wa,
                                                        const float* __restrict__ Wb,
                                                        const float* __restrict__ Wc,
                                                        u16* __restrict__ Wfa,
                                                        u16* __restrict__ Wfb,
                                                        u16* __restrict__ Wfc) {
    const float* W = (blockIdx.x == 0) ? Wa : (blockIdx.x == 1) ? Wb : Wc;
    u16* Wf = (blockIdx.x == 0) ? Wfa : (blockIdx.x == 1) ? Wfb : Wfc;
    for (int i = threadIdx.x; i < 16384; i += 256) {
        int j = i & 7;
        int lane = (i >> 3) & 63;
        int nb = (i >> 9) & 7;
        int kk = i >> 12;
        int k = kk * 32 + (lane >> 4) * 8 + j;
        int n = nb * 16 + (lane & 15);
        Wf[i] = f2h(W[k * 128 + n]);
    }
}

// ---------- layer-1 GEMM: P1' = dinv * (x @ W1), fp32 x converted in-register ----------
__global__ __launch_bounds__(256) void mfma_gemm1_kernel(const float* __restrict__ Af,
                                                         const u16* __restrict__ Wf,
                                                         const float* __restrict__ scale,
                                                         u16* __restrict__ Yh, int M) {
    __shared__ u16 sB[16384];  // 32 KB
    for (int i = threadIdx.x; i < 2048; i += 256)
        ((uint4*)sB)[i] = ((const uint4*)Wf)[i];
    __syncthreads();

    const int wid = threadIdx.x >> 6;
    const int lane = threadIdx.x & 63;
    const int lrow = lane & 15;
    const int lkb = lane >> 4;

    const int nstrip = (M + 31) / 32;
    for (int strip = blockIdx.x * 4 + wid; strip < nstrip; strip += gridDim.x * 4) {
        const int row0 = strip * 32;
        f16x8 a[2][4];
#pragma unroll
        for (int t = 0; t < 2; ++t)
#pragma unroll
            for (int kk = 0; kk < 4; ++kk) {
                const float4* p = (const float4*)&Af[(size_t)(row0 + t * 16 + lrow) * FEAT +
                                                     kk * 32 + lkb * 8];
                float4 u0 = p[0], u1 = p[1];
                f16x8 av;
                av[0] = (f16)u0.x; av[1] = (f16)u0.y; av[2] = (f16)u0.z; av[3] = (f16)u0.w;
                av[4] = (f16)u1.x; av[5] = (f16)u1.y; av[6] = (f16)u1.z; av[7] = (f16)u1.w;
                a[t][kk] = av;
            }
        f32x4 acc[2][8];
#pragma unroll
        for (int t = 0; t < 2; ++t)
#pragma unroll
            for (int nb = 0; nb < 8; ++nb) {
                acc[t][nb][0] = 0.f; acc[t][nb][1] = 0.f;
                acc[t][nb][2] = 0.f; acc[t][nb][3] = 0.f;
            }
#pragma unroll
        for (int kk = 0; kk < 4; ++kk)
#pragma unroll
            for (int nb = 0; nb < 8; ++nb) {
                f16x8 b = *(const f16x8*)&sB[((kk * 8 + nb) * 64 + lane) * 8];
                acc[0][nb] = __builtin_amdgcn_mfma_f32_16x16x32_f16(a[0][kk], b, acc[0][nb], 0, 0, 0);
                acc[1][nb] = __builtin_amdgcn_mfma_f32_16x16x32_f16(a[1][kk], b, acc[1][nb], 0, 0, 0);
            }
#pragma unroll
        for (int t = 0; t < 2; ++t)
#pragma unroll
            for (int nb = 0; nb < 8; ++nb)
#pragma unroll
                for (int r = 0; r < 4; ++r) {
                    int row = row0 + t * 16 + (lane >> 4) * 4 + r;
                    int c = nb * 16 + (lane & 15);
                    Yh[(size_t)row * FEAT + c] = f2h(acc[t][nb][r] * scale[row]);
                }
    }
}

// ---------- fused gather + next-layer GEMM (4 KB LDS; W frags from global) ----------
__global__ __launch_bounds__(256) void gather_gemm_kernel(const int* __restrict__ row_ptr,
                                                          const int* __restrict__ col,
                                                          const float* __restrict__ dinv,
                                                          const u16* __restrict__ Pin,
                                                          const float* __restrict__ aggBias,
                                                          const u16* __restrict__ Wf,
                                                          const float* __restrict__ headBias,
                                                          u16* __restrict__ Yh,
                                                          float* __restrict__ Yf, int N) {
    __shared__ u16 tile[16 * 128];  // 4 KB; XOR-swizzled rows (full 16-slot swizzle)

    const int lane16 = threadIdx.x & 15;
    const int grp = threadIdx.x >> 4;  // 0..15
    const int row0 = blockIdx.x * 16;
    const int n = row0 + grp;
    const int f8 = lane16 * 8;

    float a0 = 0.f, a1 = 0.f, a2 = 0.f, a3 = 0.f;
    float a4 = 0.f, a5 = 0.f, a6 = 0.f, a7 = 0.f;

    if (n < N) {
        const float di = dinv[n];
        {
            uint4 sv = *(const uint4*)&Pin[(size_t)n * FEAT + f8];
            float2 f0 = __half22float2(*(__half2*)&sv.x);
            float2 f1 = __half22float2(*(__half2*)&sv.y);
            float2 f2 = __half22float2(*(__half2*)&sv.z);
            float2 f3 = __half22float2(*(__half2*)&sv.w);
            a0 = f0.x; a1 = f0.y; a2 = f1.x; a3 = f1.y;
            a4 = f2.x; a5 = f2.y; a6 = f3.x; a7 = f3.y;
        }
#define ACC8(v) { \
        float2 f0 = __half22float2(*(__half2*)&(v).x); \
        float2 f1 = __half22float2(*(__half2*)&(v).y); \
        float2 f2 = __half22float2(*(__half2*)&(v).z); \
        float2 f3 = __half22float2(*(__half2*)&(v).w); \
        a0 += f0.x; a1 += f0.y; a2 += f1.x; a3 += f1.y; \
        a4 += f2.x; a5 += f2.y; a6 += f3.x; a7 += f3.y; }
        const int start = row_ptr[n];
        const int end = row_ptr[n + 1];
        for (int e0 = start; e0 < end; e0 += 16) {
            int mye = e0 + lane16;
            int s = (mye < end) ? col[mye] : -1;
            int jmax = end - e0; if (jmax > 16) jmax = 16;
            int j = 0;
            for (; j + 3 < jmax; j += 4) {
                int s0 = __shfl(s, j, 16),     s1 = __shfl(s, j + 1, 16);
                int s2 = __shfl(s, j + 2, 16), s3 = __shfl(s, j + 3, 16);
                uint4 v0 = *(const uint4*)&Pin[(size_t)s0 * FEAT + f8];
                uint4 v1 = *(const uint4*)&Pin[(size_t)s1 * FEAT + f8];
                uint4 v2 = *(const uint4*)&Pin[(size_t)s2 * FEAT + f8];
                uint4 v3 = *(const uint4*)&Pin[(size_t)s3 * FEAT + f8];
                ACC8(v0); ACC8(v1); ACC8(v2); ACC8(v3);
            }
            for (; j < jmax; ++j) {
                int s0 = __shfl(s, j, 16);
                uint4 v0 = *(const uint4*)&Pin[(size_t)s0 * FEAT + f8];
                ACC8(v0);
            }
        }
#undef ACC8
        const float4 b0 = *(const float4*)&aggBias[f8];
        const float4 b1 = *(const float4*)&aggBias[f8 + 4];
        a0 = fmaxf(a0 * di + b0.x, 0.f); a1 = fmaxf(a1 * di + b0.y, 0.f);
        a2 = fmaxf(a2 * di + b0.z, 0.f); a3 = fmaxf(a3 * di + b0.w, 0.f);
        a4 = fmaxf(a4 * di + b1.x, 0.f); a5 = fmaxf(a5 * di + b1.y, 0.f);
        a6 = fmaxf(a6 * di + b1.z, 0.f); a7 = fmaxf(a7 * di + b1.w, 0.f);
    }

    // write h row into swizzled LDS tile (zeros for n >= N)
    {
        f16x8 hv;
        hv[0] = (f16)a0; hv[1] = (f16)a1; hv[2] = (f16)a2; hv[3] = (f16)a3;
        hv[4] = (f16)a4; hv[5] = (f16)a5; hv[6] = (f16)a6; hv[7] = (f16)a7;
        *(f16x8*)&tile[grp * 128 + ((lane16 * 8) ^ ((grp & 15) << 3))] = hv;
    }
    __syncthreads();

    // Phase 2: 4 waves x 2 n-blocks; A-frags from swizzled tile, B-frags from global
    const int lane = threadIdx.x & 63;
    const int wid = threadIdx.x >> 6;
    const int trow = lane & 15;
    f16x8 af[4];
#pragma unroll
    for (int kk = 0; kk < 4; ++kk)
        af[kk] = *(const f16x8*)&tile[trow * 128 +
                                      ((kk * 32 + (lane >> 4) * 8) ^ ((trow & 15) << 3))];
#pragma unroll
    for (int nb2 = 0; nb2 < 2; ++nb2) {
        const int nb = wid * 2 + nb2;
        f32x4 acc;
        acc[0] = 0.f; acc[1] = 0.f; acc[2] = 0.f; acc[3] = 0.f;
#pragma unroll
        for (int kk = 0; kk < 4; ++kk) {
            f16x8 b = *(const f16x8*)&Wf[((kk * 8 + nb) * 64 + lane) * 8];
            acc = __builtin_amdgcn_mfma_f32_16x16x32_f16(af[kk], b, acc, 0, 0, 0);
        }
        const int c = nb * 16 + (lane & 15);
#pragma unroll
        for (int r = 0; r < 4; ++r) {
            int row = row0 + (lane >> 4) * 4 + r;
            if (row < N) {
                float v = acc[r];
                if (Yh) {
                    Yh[(size_t)row * FEAT + c] = f2h(v * dinv[row]);
                } else {
                    Yf[(size_t)row * FEAT + c] = v + headBias[c];
                }
            }
        }
    }
}

extern "C" void kernel_launch(void* const* d_in, const int* in_sizes, int n_in,
                              void* d_out, int out_size, void* d_ws, size_t ws_size,
                              hipStream_t stream) {
    const float* x  = (const float*)d_in[0];
    const int*   ei = (const int*)d_in[1];
    const float* W1 = (const float*)d_in[2];
    const float* b1 = (const float*)d_in[3];
    const float* W2 = (const float*)d_in[4];
    const float* b2 = (const float*)d_in[5];
    const float* Wl = (const float*)d_in[6];
    const float* bl = (const float*)d_in[7];
    float* out = (float*)d_out;

    const int N = in_sizes[0] / FEAT;      // 100000
    const long long E = in_sizes[1] / 2;   // 3200000
    const int* src = ei;
    const int* dst = ei + E;

    const int nbuck = (N + NPB - 1) >> NPB_SHIFT;    // 196
    const int nchunks = (int)((E + EPB - 1) / EPB);  // 782
    const int nblk = ((nchunks + 7) / 8) * 8;        // 784

    // workspace layout (~68 MB)
    u16*   PbA     = (u16*)d_ws;                       // N*128 fp16 (aliases ebuf)
    u16*   PbB     = PbA + (long long)N * FEAT;        // N*128 fp16
    float* dinv    = (float*)(PbB + (long long)N * FEAT);
    int*   row_ptr = (int*)(dinv + N);                 // N+1
    int*   btot    = row_ptr + N + 1;                  // 256
    int*   bbase   = btot + 256;                       // 256
    int*   cmat    = bbase + 256;                      // nbuck*nblk
    u16*   Wf1     = (u16*)(cmat + (long long)nbuck * nblk);  // 16384
    u16*   Wf2     = Wf1 + 16384;
    u16*   Wfl     = Wf2 + 16384;
    int*   col     = (int*)(Wfl + 16384);              // E
    u32*   ebuf    = (u32*)PbA;                        // E u32 (12.8MB, in PbA)

    // ---- bucket radix: sort edges by dst bucket (packed u32) ----
    radix_count_kernel<<<nblk, 256, 0, stream>>>(dst, cmat, E, nbuck, nblk);
    radix_btot_kernel<<<nbuck, 256, 0, stream>>>(cmat, btot, nblk);
    radix_bscan_kernel<<<1, 256, 0, stream>>>(btot, bbase, nbuck);
    radix_colscan_kernel<<<nbuck, 256, 0, stream>>>(cmat, bbase, nblk);
    radix_scatter_kernel<<<nblk, 256, 0, stream>>>(src, dst, cmat, ebuf, E, nbuck, nblk);

    // ---- per-bucket finisher: row_ptr, dinv, col (consumes ebuf) ----
    bucket_finish_kernel<<<nbuck, 1024, 0, stream>>>(ebuf, bbase, btot, col, row_ptr,
                                                     dinv, N, nbuck, E);

    // ---- weight prepack ----
    prepack_w_kernel<<<3, 256, 0, stream>>>(W1, W2, Wl, Wf1, Wf2, Wfl);

    const int gemmGrid = ((N + 31) / 32 + 3) / 4;
    const int fusedGrid = (N + 15) / 16;

    // ---- layer 1 projection: P1' = dinv * (x @ W1) (writes PbA; ebuf consumed) ----
    mfma_gemm1_kernel<<<gemmGrid, 256, 0, stream>>>(x, Wf1, dinv, PbA, N);

    // ---- h1 agg + layer-2 projection: P2' = dinv * (relu(agg)@W2) ----
    gather_gemm_kernel<<<fusedGrid, 256, 0, stream>>>(row_ptr, col, dinv, PbA, b1,
                                                      Wf2, nullptr, PbB, nullptr, N);

    // ---- h2 agg + head: out = relu(agg) @ Wl + bl ----
    gather_gemm_kernel<<<fusedGrid, 256, 0, stream>>>(row_ptr, col, dinv, PbB, b2,
                                                      Wfl, bl, nullptr, out, N);
}